// Round 1
// baseline (1085.983 us; speedup 1.0000x reference)
//
#include <hip/hip_runtime.h>
#include <hip/hip_bf16.h>

#define B_ 8
#define T_ 8192
#define DNA_ 4
#define HID_ 256
#define C_ 5
#define K_ 16

__device__ __forceinline__ float gelu_tanh(float x) {
    // JAX approximate gelu: 0.5*x*(1+tanh(0.7978845608*(x+0.044715*x^3)))
    float u = 0.7978845608028654f * (x + 0.044715f * x * x * x);
    float e = __expf(2.0f * u);
    float th = 1.0f - 2.0f / (e + 1.0f);
    return 0.5f * x * (1.0f + th);
}

// Kernel A: fused encoder -> emit[b][c][t] (transposed layout for the cumsum kernel)
__global__ __launch_bounds__(256) void encoder_kernel(
    const float* __restrict__ seq, const float* __restrict__ W_enc,
    const float* __restrict__ b_enc, const float* __restrict__ W_proj,
    const float* __restrict__ b_proj, float* __restrict__ emit)
{
    __shared__ float4 we[HID_];       // W_enc transposed: [h] -> (k=0..3)
    __shared__ float  be[HID_];
    __shared__ float  wp[HID_ * C_];  // W_proj [h][c]
    int tid = threadIdx.x;
    {
        int h = tid; // blockDim == HID_
        we[h] = make_float4(W_enc[0*HID_+h], W_enc[1*HID_+h], W_enc[2*HID_+h], W_enc[3*HID_+h]);
        be[h] = b_enc[h];
        for (int i = tid; i < HID_*C_; i += 256) wp[i] = W_proj[i];
    }
    __syncthreads();
    int gid = blockIdx.x * 256 + tid;
    int b = gid >> 13;           // / T_
    int t = gid & (T_ - 1);      // % T_
    float4 s = reinterpret_cast<const float4*>(seq)[(size_t)b * T_ + t];
    float a0 = b_proj[0], a1 = b_proj[1], a2 = b_proj[2], a3 = b_proj[3], a4 = b_proj[4];
    #pragma unroll 8
    for (int h = 0; h < HID_; ++h) {
        float4 w = we[h];
        float pre = be[h] + s.x*w.x + s.y*w.y + s.z*w.z + s.w*w.w;
        float hd = gelu_tanh(pre);
        a0 = fmaf(hd, wp[h*C_+0], a0);
        a1 = fmaf(hd, wp[h*C_+1], a1);
        a2 = fmaf(hd, wp[h*C_+2], a2);
        a3 = fmaf(hd, wp[h*C_+3], a3);
        a4 = fmaf(hd, wp[h*C_+4], a4);
    }
    size_t base = (size_t)b * C_ * T_ + t;
    emit[base + 0*T_] = a0;
    emit[base + 1*T_] = a1;
    emit[base + 2*T_] = a2;
    emit[base + 3*T_] = a3;
    emit[base + 4*T_] = a4;
}

// Kernel B: per-(b,c) inclusive cumsum of emit over t -> cum (B, T+1, C) in d_out
__global__ __launch_bounds__(64) void cumsum_kernel(
    const float* __restrict__ emit, float* __restrict__ cum)
{
    int bc = blockIdx.x;
    int b = bc / C_, c = bc - b * C_;
    int lane = threadIdx.x;
    const float* e = emit + (size_t)bc * T_;
    float* cb = cum + (size_t)b * (T_ + 1) * C_;
    if (lane == 0) cb[c] = 0.0f;
    float carry = 0.0f;
    for (int chunk = 0; chunk < T_ / 64; ++chunk) {
        int t = chunk * 64 + lane;
        float v = e[t];
        #pragma unroll
        for (int off = 1; off < 64; off <<= 1) {
            float n = __shfl_up(v, off, 64);
            if (lane >= off) v += n;
        }
        v += carry;
        cb[(size_t)(t + 1) * C_ + c] = v;
        carry = __shfl(v, 63, 64);
    }
}

// Kernel C: sequential semi-CRF forward in exp space. One block per batch,
// lanes 0..4 = classes, 16-slot ring of Q in registers (fully unrolled).
__global__ __launch_bounds__(64) void scan_kernel(
    const float* __restrict__ cum, const int* __restrict__ lengths,
    const float* __restrict__ trans, const float* __restrict__ startv,
    const float* __restrict__ dur, float* __restrict__ partition)
{
    int b = blockIdx.x;
    int lane = threadIdx.x;
    if (lane >= C_) return;
    int c = lane;
    const float* cb = cum + (size_t)b * (T_ + 1) * C_ + c; // index with t*C_
    int len = lengths[b];

    float ed[K_];
    #pragma unroll
    for (int j = 0; j < K_; ++j) ed[j] = __expf(dur[c * K_ + j]);
    float e5[C_];
    #pragma unroll
    for (int k = 0; k < C_; ++k) e5[k] = __expf(trans[k * C_ + c]);

    float Q[K_];
    #pragma unroll
    for (int s = 0; s < K_; ++s) Q[s] = 0.0f;
    Q[0] = __expf(startv[c]);   // H0[0]=start, rest = -inf -> 0 in exp space

    float Z = 0.0f, sA = 0.0f, sZ = 0.0f;
    float cv[17], nv[17];
    #pragma unroll
    for (int i = 0; i < 17; ++i) cv[i] = cb[(size_t)i * C_]; // cum[0..16]

    for (int tb = 1; tb <= len; tb += K_) {
        // prefetch next block's cum[tb+15 .. tb+31] (clamped)
        #pragma unroll
        for (int i = 0; i < 17; ++i) {
            int idx = tb + 15 + i;
            idx = idx > T_ ? T_ : idx;
            nv[i] = cb[(size_t)idx * C_];
        }
        float g[K_];
        #pragma unroll
        for (int p = 0; p < K_; ++p) g[p] = __expf(cv[p + 1] - cv[p]);

        #pragma unroll
        for (int p = 0; p < K_; ++p) {
            int t = tb + p;
            #pragma unroll
            for (int s = 0; s < K_; ++s) Q[s] *= g[p];
            // a[c] = sum_j Q[j]*exp(dur[c,j]);  slot s holds j=(s+p)&15 (tb==1 mod 16)
            float p0 = 0.f, p1 = 0.f, p2 = 0.f, p3 = 0.f;
            #pragma unroll
            for (int s = 0; s < K_; s += 4) {
                p0 = fmaf(Q[s + 0], ed[(s + 0 + p) & 15], p0);
                p1 = fmaf(Q[s + 1], ed[(s + 1 + p) & 15], p1);
                p2 = fmaf(Q[s + 2], ed[(s + 2 + p) & 15], p2);
                p3 = fmaf(Q[s + 3], ed[(s + 3 + p) & 15], p3);
            }
            float a = (p0 + p1) + (p2 + p3);
            float av0 = __shfl(a, 0, 64);
            float av1 = __shfl(a, 1, 64);
            float av2 = __shfl(a, 2, 64);
            float av3 = __shfl(a, 3, 64);
            float av4 = __shfl(a, 4, 64);
            float Mx = e5[0]*av0 + e5[1]*av1 + e5[2]*av2 + e5[3]*av3 + e5[4]*av4;
            Q[15 - p] = Mx;        // recycled slot becomes j=0 at t+1
            if (t == len) { sA = a; sZ = Z; }
            if ((t & 7) == 0) {    // renorm every 8 steps, batch-uniform factor
                float r = __builtin_amdgcn_rcpf(av0);
                #pragma unroll
                for (int s = 0; s < K_; ++s) Q[s] *= r;
                Z += __logf(av0);
            }
        }
        #pragma unroll
        for (int i = 0; i < 17; ++i) cv[i] = nv[i];
    }
    // partition[b] = Z_saved + log(sum_c exp(alpha - Z)) at t == len
    float s0 = __shfl(sA, 0, 64) + __shfl(sA, 1, 64) + __shfl(sA, 2, 64)
             + __shfl(sA, 3, 64) + __shfl(sA, 4, 64);
    if (lane == 0) partition[b] = sZ + __logf(s0);
}

extern "C" void kernel_launch(void* const* d_in, const int* in_sizes, int n_in,
                              void* d_out, int out_size, void* d_ws, size_t ws_size,
                              hipStream_t stream) {
    (void)in_sizes; (void)n_in; (void)out_size; (void)ws_size;
    const float* seq    = (const float*)d_in[0];
    const int*   lens   = (const int*)  d_in[1];
    const float* W_enc  = (const float*)d_in[2];
    const float* b_enc  = (const float*)d_in[3];
    const float* W_proj = (const float*)d_in[4];
    const float* b_proj = (const float*)d_in[5];
    const float* trans  = (const float*)d_in[6];
    const float* startv = (const float*)d_in[7];
    const float* dur    = (const float*)d_in[8];

    float* out       = (float*)d_out;
    float* partition = out;        // (B,)
    float* cum       = out + B_;   // (B, T+1, C)
    float* emit      = (float*)d_ws; // B*C*T floats = 1.31 MB scratch

    encoder_kernel<<<(B_ * T_) / 256, 256, 0, stream>>>(seq, W_enc, b_enc, W_proj, b_proj, emit);
    cumsum_kernel<<<B_ * C_, 64, 0, stream>>>(emit, cum);
    scan_kernel<<<B_, 64, 0, stream>>>(cum, lens, trans, startv, dur, partition);
}

// Round 2
// 245.597 us; speedup vs baseline: 4.4218x; 4.4218x over previous
//
#include <hip/hip_runtime.h>
#include <hip/hip_bf16.h>

#define B_ 8
#define T_ 8192
#define DNA_ 4
#define HID_ 256
#define C_ 5
#define K_ 16
#define NC_ 32   // chunks per batch for the parallel scan

__device__ __forceinline__ float gelu_tanh(float x) {
    float u = 0.7978845608028654f * (x + 0.044715f * x * x * x);
    float e = __expf(2.0f * u);
    float th = 1.0f - 2.0f / (e + 1.0f);
    return 0.5f * x * (1.0f + th);
}

// ---------------- Kernel A: encoder -> emit[b][c][t] ----------------
__global__ __launch_bounds__(256) void encoder_kernel(
    const float* __restrict__ seq, const float* __restrict__ W_enc,
    const float* __restrict__ b_enc, const float* __restrict__ W_proj,
    const float* __restrict__ b_proj, float* __restrict__ emit)
{
    __shared__ float4 we[HID_];
    __shared__ float  be[HID_];
    __shared__ float  wp[HID_ * C_];
    int tid = threadIdx.x;
    {
        int h = tid;
        we[h] = make_float4(W_enc[0*HID_+h], W_enc[1*HID_+h], W_enc[2*HID_+h], W_enc[3*HID_+h]);
        be[h] = b_enc[h];
        for (int i = tid; i < HID_*C_; i += 256) wp[i] = W_proj[i];
    }
    __syncthreads();
    int gid = blockIdx.x * 256 + tid;
    int b = gid >> 13;
    int t = gid & (T_ - 1);
    float4 s = reinterpret_cast<const float4*>(seq)[(size_t)b * T_ + t];
    float a0 = b_proj[0], a1 = b_proj[1], a2 = b_proj[2], a3 = b_proj[3], a4 = b_proj[4];
    #pragma unroll 8
    for (int h = 0; h < HID_; ++h) {
        float4 w = we[h];
        float pre = be[h] + s.x*w.x + s.y*w.y + s.z*w.z + s.w*w.w;
        float hd = gelu_tanh(pre);
        a0 = fmaf(hd, wp[h*C_+0], a0);
        a1 = fmaf(hd, wp[h*C_+1], a1);
        a2 = fmaf(hd, wp[h*C_+2], a2);
        a3 = fmaf(hd, wp[h*C_+3], a3);
        a4 = fmaf(hd, wp[h*C_+4], a4);
    }
    size_t base = (size_t)b * C_ * T_ + t;
    emit[base + 0*T_] = a0;
    emit[base + 1*T_] = a1;
    emit[base + 2*T_] = a2;
    emit[base + 3*T_] = a3;
    emit[base + 4*T_] = a4;
}

// ---------------- Kernel B: block-parallel cumsum -> cum (B,T+1,C) ----------------
__global__ __launch_bounds__(256) void cumsum_kernel(
    const float* __restrict__ emit, float* __restrict__ cum)
{
    int bc = blockIdx.x;
    int b = bc / C_, c = bc - b * C_;
    int tid = threadIdx.x;
    int lane = tid & 63, wv = tid >> 6;
    const float* e = emit + (size_t)bc * T_;
    float* cb = cum + (size_t)b * (T_ + 1) * C_ + c;

    float v[32];
    float sum = 0.0f;
    const float4* e4 = reinterpret_cast<const float4*>(e + tid * 32);
    #pragma unroll
    for (int i = 0; i < 8; ++i) {
        float4 f = e4[i];
        v[i*4+0] = f.x; v[i*4+1] = f.y; v[i*4+2] = f.z; v[i*4+3] = f.w;
        sum += (f.x + f.y) + (f.z + f.w);
    }
    // inclusive wave scan of per-thread sums
    float si = sum;
    #pragma unroll
    for (int off = 1; off < 64; off <<= 1) {
        float n = __shfl_up(si, off, 64);
        if (lane >= off) si += n;
    }
    __shared__ float wtot[4];
    if (lane == 63) wtot[wv] = si;
    __syncthreads();
    float carry = 0.0f;
    #pragma unroll
    for (int w2 = 0; w2 < 3; ++w2) if (w2 < wv) carry += wtot[w2];
    float run = si - sum + carry;   // exclusive prefix for this thread
    if (tid == 0) cb[0] = 0.0f;
    #pragma unroll
    for (int i = 0; i < 32; ++i) {
        run += v[i];
        cb[(size_t)(tid * 32 + i + 1) * C_] = run;
    }
}

// ---------------- Kernel C: per-chunk 80x80 transfer matrices ----------------
// Block = (b, k). 448 threads: wave w, lane l -> column col = w*12 + l/5 (80 basis
// columns of the chunk transfer matrix), class c = l%5. Each thread propagates its
// column's Q-ring (16 slots, own class) through the chunk's steps.
__global__ __launch_bounds__(448) void chunk_kernel(
    const float* __restrict__ emit, const float* __restrict__ cum,
    const int* __restrict__ lengths, const float* __restrict__ trans,
    const float* __restrict__ dur, float* __restrict__ Mout,
    float* __restrict__ Rout, float* __restrict__ Zout)
{
    __shared__ float g_lds[C_][260];
    int blk = blockIdx.x;
    int b = blk >> 5, k = blk & (NC_ - 1);
    int len = lengths[b];
    int s = (k * len) / NC_;
    int e = ((k + 1) * len) / NC_;
    int L = e - s;                      // 128..256
    int tid = threadIdx.x;

    const float* eb = emit + (size_t)b * C_ * T_;
    for (int cc = 0; cc < C_; ++cc)
        for (int tl = tid; tl < L; tl += 448)
            g_lds[cc][tl] = __expf(eb[cc * T_ + s + tl]);   // g for step t=s+1+tl is exp(emit[s+tl])
    __syncthreads();

    int lane = tid & 63, wv = tid >> 6;
    int cin = lane / 5;
    int c = lane - cin * C_;
    int col = wv * 12 + cin;
    bool active = (cin < 12) && (col < 80);
    int base5 = (cin < 12) ? (lane - c) : 0;

    const float* cb = cum + (size_t)b * (T_ + 1) * C_;

    float ed[K_], eT[C_];
    #pragma unroll
    for (int j = 0; j < K_; ++j) ed[j] = __expf(dur[c * K_ + j]);
    #pragma unroll
    for (int cc = 0; cc < C_; ++cc) eT[cc] = __expf(trans[cc * C_ + c]);

    float Q[K_];
    #pragma unroll
    for (int j = 0; j < K_; ++j) Q[j] = 0.0f;
    {
        int j0 = col / C_;
        int c0 = col - j0 * C_;
        if (active && c == c0) {
            int i1 = s - j0; if (i1 < 0) i1 = 0;
            float val = __expf(cb[(size_t)s * C_ + c] - cb[(size_t)i1 * C_ + c]);
            #pragma unroll
            for (int j = 0; j < K_; ++j) if (j == j0) Q[j] = val;
        }
    }

    float z = 0.0f, zfin = 0.0f, Afin = 0.0f;
    float Qc[K_];
    #pragma unroll
    for (int j = 0; j < K_; ++j) Qc[j] = 0.0f;

    for (int bs = 0; bs < L; bs += K_) {
        #pragma unroll
        for (int p = 0; p < K_; ++p) {
            int tl = bs + p;
            if (tl < L) {
                float g = g_lds[c][tl];
                #pragma unroll
                for (int q = 0; q < K_; ++q) Q[q] *= g;
                float d0 = 0.f, d1 = 0.f, d2 = 0.f, d3 = 0.f;
                #pragma unroll
                for (int q = 0; q < K_; q += 4) {
                    d0 = fmaf(Q[q+0], ed[(q+0+p) & 15], d0);
                    d1 = fmaf(Q[q+1], ed[(q+1+p) & 15], d1);
                    d2 = fmaf(Q[q+2], ed[(q+2+p) & 15], d2);
                    d3 = fmaf(Q[q+3], ed[(q+3+p) & 15], d3);
                }
                float A = (d0 + d1) + (d2 + d3);
                float A0 = __shfl(A, base5 + 0, 64);
                float A1 = __shfl(A, base5 + 1, 64);
                float A2 = __shfl(A, base5 + 2, 64);
                float A3 = __shfl(A, base5 + 3, 64);
                float A4 = __shfl(A, base5 + 4, 64);
                float Sn = fmaf(eT[0], A0, fmaf(eT[1], A1, fmaf(eT[2], A2,
                           fmaf(eT[3], A3, eT[4] * A4))));
                Q[15 - p] = Sn;
                if (tl == L - 1) {
                    #pragma unroll
                    for (int j = 0; j < K_; ++j) Qc[j] = Q[(j + 15 - p) & 15];
                    Afin = A; zfin = z;
                }
                if (((p + 1) & 7) == 0) {   // every 8 local steps (static)
                    bool ok = (A0 > 1e-30f);
                    float r  = ok ? __builtin_amdgcn_rcpf(A0) : 1.0f;
                    float lz = ok ? __logf(A0) : 0.0f;
                    #pragma unroll
                    for (int q = 0; q < K_; ++q) Q[q] *= r;
                    z += lz;
                }
            }
        }
    }

    if (active) {
        float ce = cb[(size_t)e * C_ + c];
        size_t ob = ((size_t)blk * 80 + col) * 80;
        #pragma unroll
        for (int j = 0; j < K_; ++j) {
            float ratio = __expf(cb[(size_t)(e - j) * C_ + c] - ce);
            Mout[ob + j * C_ + c] = Qc[j] * ratio;
        }
        Rout[(size_t)blk * 400 + col * C_ + c] = Afin;
        if (c == 0) Zout[(size_t)blk * 80 + col] = zfin;
    }
}

// ---------------- Kernel D: sequential combine (32 matvecs per batch) ----------------
__global__ __launch_bounds__(512) void combine_kernel(
    const float* __restrict__ Mst, const float* __restrict__ Rst,
    const float* __restrict__ Zst, const float* __restrict__ startv,
    float* __restrict__ partition)
{
    int b = blockIdx.x;
    int tid = threadIdx.x;
    __shared__ float xs[80], ws[80], zv[80], red[2];
    __shared__ float part[6][80];

    if (tid < 80) xs[tid] = (tid < C_) ? __expf(startv[tid]) : 0.0f;
    float Z = 0.0f;
    __syncthreads();

    for (int k = 0; k < NC_; ++k) {
        size_t blk = (size_t)b * NC_ + k;
        if (tid < 80) zv[tid] = (xs[tid] > 0.0f) ? Zst[blk * 80 + tid] : -3e38f;
        __syncthreads();
        if (tid < 64) {
            float m = zv[tid];
            if (tid < 16) m = fmaxf(m, zv[tid + 64]);
            #pragma unroll
            for (int off = 32; off; off >>= 1) m = fmaxf(m, __shfl_xor(m, off, 64));
            if (tid == 0) red[0] = m;
        }
        __syncthreads();
        float zmax = red[0];
        if (tid < 80) ws[tid] = (xs[tid] > 0.0f) ? xs[tid] * __expf(zv[tid] - zmax) : 0.0f;
        __syncthreads();

        if (k < NC_ - 1) {
            int i = tid % 80, q = tid / 80;
            if (tid < 480) {
                float p = 0.0f;
                const float* mcol = Mst + blk * 6400 + i;
                for (int j = q; j < 80; j += 6)
                    p = fmaf(mcol[(size_t)j * 80], ws[j], p);
                part[q][i] = p;
            }
            __syncthreads();
            if (tid < 80) {
                float y = ((part[0][tid] + part[1][tid]) + (part[2][tid] + part[3][tid]))
                        + (part[4][tid] + part[5][tid]);
                zv[tid] = y;
            }
            __syncthreads();
            if (tid < 64) {
                float m = zv[tid];
                if (tid < 16) m = fmaxf(m, zv[tid + 64]);
                #pragma unroll
                for (int off = 32; off; off >>= 1) m = fmaxf(m, __shfl_xor(m, off, 64));
                if (tid == 0) red[1] = m;
            }
            __syncthreads();
            float ym = red[1];
            if (tid < 80) xs[tid] = zv[tid] / ym;
            Z += zmax + __logf(ym);
            __syncthreads();
        } else {
            if (tid < 80) {
                float wi = ws[tid];
                const float* rrow = Rst + blk * 400 + tid * C_;
                #pragma unroll
                for (int cc = 0; cc < C_; ++cc) part[cc][tid] = wi * rrow[cc];
            }
            __syncthreads();
            if (tid < C_) {
                float t = 0.0f;
                for (int i = 0; i < 80; ++i) t += part[tid][i];
                zv[tid] = t;
            }
            __syncthreads();
            if (tid == 0) {
                float tot = (zv[0] + zv[1]) + (zv[2] + zv[3]) + zv[4];
                partition[b] = Z + zmax + __logf(tot);
            }
            __syncthreads();
        }
    }
}

extern "C" void kernel_launch(void* const* d_in, const int* in_sizes, int n_in,
                              void* d_out, int out_size, void* d_ws, size_t ws_size,
                              hipStream_t stream) {
    (void)in_sizes; (void)n_in; (void)out_size; (void)ws_size;
    const float* seq    = (const float*)d_in[0];
    const int*   lens   = (const int*)  d_in[1];
    const float* W_enc  = (const float*)d_in[2];
    const float* b_enc  = (const float*)d_in[3];
    const float* W_proj = (const float*)d_in[4];
    const float* b_proj = (const float*)d_in[5];
    const float* trans  = (const float*)d_in[6];
    const float* startv = (const float*)d_in[7];
    const float* dur    = (const float*)d_in[8];

    float* out       = (float*)d_out;
    float* partition = out;
    float* cum       = out + B_;

    float* emit = (float*)d_ws;                       // B*C*T
    float* Mst  = emit + (size_t)B_ * C_ * T_;        // B*NC*80*80
    float* Rst  = Mst  + (size_t)B_ * NC_ * 6400;     // B*NC*80*5
    float* Zst  = Rst  + (size_t)B_ * NC_ * 400;      // B*NC*80

    encoder_kernel<<<(B_ * T_) / 256, 256, 0, stream>>>(seq, W_enc, b_enc, W_proj, b_proj, emit);
    cumsum_kernel<<<B_ * C_, 256, 0, stream>>>(emit, cum);
    chunk_kernel<<<B_ * NC_, 448, 0, stream>>>(emit, cum, lens, trans, dur, Mst, Rst, Zst);
    combine_kernel<<<B_, 512, 0, stream>>>(Mst, Rst, Zst, startv, partition);
}

// Round 3
// 197.959 us; speedup vs baseline: 5.4859x; 1.2406x over previous
//
#include <hip/hip_runtime.h>
#include <hip/hip_bf16.h>

#define B_ 8
#define T_ 8192
#define DNA_ 4
#define HID_ 256
#define C_ 5
#define K_ 16
#define NC_ 32   // chunks per batch for the parallel scan

__device__ __forceinline__ float gelu_tanh(float x) {
    float u = 0.7978845608028654f * (x + 0.044715f * x * x * x);
    float e = __expf(2.0f * u);
    float th = 1.0f - 2.0f / (e + 1.0f);
    return 0.5f * x * (1.0f + th);
}

// ---------------- Kernel A: encoder -> emit[b][c][t] ----------------
__global__ __launch_bounds__(256) void encoder_kernel(
    const float* __restrict__ seq, const float* __restrict__ W_enc,
    const float* __restrict__ b_enc, const float* __restrict__ W_proj,
    const float* __restrict__ b_proj, float* __restrict__ emit)
{
    __shared__ float4 we[HID_];
    __shared__ float  be[HID_];
    __shared__ float  wp[HID_ * C_];
    int tid = threadIdx.x;
    {
        int h = tid;
        we[h] = make_float4(W_enc[0*HID_+h], W_enc[1*HID_+h], W_enc[2*HID_+h], W_enc[3*HID_+h]);
        be[h] = b_enc[h];
        for (int i = tid; i < HID_*C_; i += 256) wp[i] = W_proj[i];
    }
    __syncthreads();
    int gid = blockIdx.x * 256 + tid;
    int b = gid >> 13;
    int t = gid & (T_ - 1);
    float4 s = reinterpret_cast<const float4*>(seq)[(size_t)b * T_ + t];
    float a0 = b_proj[0], a1 = b_proj[1], a2 = b_proj[2], a3 = b_proj[3], a4 = b_proj[4];
    #pragma unroll 8
    for (int h = 0; h < HID_; ++h) {
        float4 w = we[h];
        float pre = be[h] + s.x*w.x + s.y*w.y + s.z*w.z + s.w*w.w;
        float hd = gelu_tanh(pre);
        a0 = fmaf(hd, wp[h*C_+0], a0);
        a1 = fmaf(hd, wp[h*C_+1], a1);
        a2 = fmaf(hd, wp[h*C_+2], a2);
        a3 = fmaf(hd, wp[h*C_+3], a3);
        a4 = fmaf(hd, wp[h*C_+4], a4);
    }
    size_t base = (size_t)b * C_ * T_ + t;
    emit[base + 0*T_] = a0;
    emit[base + 1*T_] = a1;
    emit[base + 2*T_] = a2;
    emit[base + 3*T_] = a3;
    emit[base + 4*T_] = a4;
}

// ---------------- Kernel B: block-parallel cumsum -> cum (B,T+1,C) ----------------
__global__ __launch_bounds__(256) void cumsum_kernel(
    const float* __restrict__ emit, float* __restrict__ cum)
{
    int bc = blockIdx.x;
    int b = bc / C_, c = bc - b * C_;
    int tid = threadIdx.x;
    int lane = tid & 63, wv = tid >> 6;
    const float* e = emit + (size_t)bc * T_;
    float* cb = cum + (size_t)b * (T_ + 1) * C_ + c;

    float v[32];
    float sum = 0.0f;
    const float4* e4 = reinterpret_cast<const float4*>(e + tid * 32);
    #pragma unroll
    for (int i = 0; i < 8; ++i) {
        float4 f = e4[i];
        v[i*4+0] = f.x; v[i*4+1] = f.y; v[i*4+2] = f.z; v[i*4+3] = f.w;
        sum += (f.x + f.y) + (f.z + f.w);
    }
    float si = sum;
    #pragma unroll
    for (int off = 1; off < 64; off <<= 1) {
        float n = __shfl_up(si, off, 64);
        if (lane >= off) si += n;
    }
    __shared__ float wtot[4];
    if (lane == 63) wtot[wv] = si;
    __syncthreads();
    float carry = 0.0f;
    #pragma unroll
    for (int w2 = 0; w2 < 3; ++w2) if (w2 < wv) carry += wtot[w2];
    float run = si - sum + carry;
    if (tid == 0) cb[0] = 0.0f;
    #pragma unroll
    for (int i = 0; i < 32; ++i) {
        run += v[i];
        cb[(size_t)(tid * 32 + i + 1) * C_] = run;
    }
}

// ---------------- Kernel C: per-chunk 80x80 transfer matrices ----------------
__global__ __launch_bounds__(448) void chunk_kernel(
    const float* __restrict__ emit, const float* __restrict__ cum,
    const int* __restrict__ lengths, const float* __restrict__ trans,
    const float* __restrict__ dur, float* __restrict__ Mout,
    float* __restrict__ Rout, float* __restrict__ Zout)
{
    __shared__ float g_lds[C_][260];
    int blk = blockIdx.x;
    int b = blk >> 5, k = blk & (NC_ - 1);
    int len = lengths[b];
    int s = (k * len) / NC_;
    int e = ((k + 1) * len) / NC_;
    int L = e - s;
    int tid = threadIdx.x;

    const float* eb = emit + (size_t)b * C_ * T_;
    for (int cc = 0; cc < C_; ++cc)
        for (int tl = tid; tl < L; tl += 448)
            g_lds[cc][tl] = __expf(eb[cc * T_ + s + tl]);
    __syncthreads();

    int lane = tid & 63, wv = tid >> 6;
    int cin = lane / 5;
    int c = lane - cin * C_;
    int col = wv * 12 + cin;
    bool active = (cin < 12) && (col < 80);
    int base5 = (cin < 12) ? (lane - c) : 0;

    const float* cb = cum + (size_t)b * (T_ + 1) * C_;

    float ed[K_], eT[C_];
    #pragma unroll
    for (int j = 0; j < K_; ++j) ed[j] = __expf(dur[c * K_ + j]);
    #pragma unroll
    for (int cc = 0; cc < C_; ++cc) eT[cc] = __expf(trans[cc * C_ + c]);

    float Q[K_];
    #pragma unroll
    for (int j = 0; j < K_; ++j) Q[j] = 0.0f;
    {
        int j0 = col / C_;
        int c0 = col - j0 * C_;
        if (active && c == c0) {
            int i1 = s - j0; if (i1 < 0) i1 = 0;
            float val = __expf(cb[(size_t)s * C_ + c] - cb[(size_t)i1 * C_ + c]);
            #pragma unroll
            for (int j = 0; j < K_; ++j) if (j == j0) Q[j] = val;
        }
    }

    float z = 0.0f, zfin = 0.0f, Afin = 0.0f;
    float Qc[K_];
    #pragma unroll
    for (int j = 0; j < K_; ++j) Qc[j] = 0.0f;

    for (int bs = 0; bs < L; bs += K_) {
        #pragma unroll
        for (int p = 0; p < K_; ++p) {
            int tl = bs + p;
            if (tl < L) {
                float g = g_lds[c][tl];
                #pragma unroll
                for (int q = 0; q < K_; ++q) Q[q] *= g;
                float d0 = 0.f, d1 = 0.f, d2 = 0.f, d3 = 0.f;
                #pragma unroll
                for (int q = 0; q < K_; q += 4) {
                    d0 = fmaf(Q[q+0], ed[(q+0+p) & 15], d0);
                    d1 = fmaf(Q[q+1], ed[(q+1+p) & 15], d1);
                    d2 = fmaf(Q[q+2], ed[(q+2+p) & 15], d2);
                    d3 = fmaf(Q[q+3], ed[(q+3+p) & 15], d3);
                }
                float A = (d0 + d1) + (d2 + d3);
                float A0 = __shfl(A, base5 + 0, 64);
                float A1 = __shfl(A, base5 + 1, 64);
                float A2 = __shfl(A, base5 + 2, 64);
                float A3 = __shfl(A, base5 + 3, 64);
                float A4 = __shfl(A, base5 + 4, 64);
                float Sn = fmaf(eT[0], A0, fmaf(eT[1], A1, fmaf(eT[2], A2,
                           fmaf(eT[3], A3, eT[4] * A4))));
                Q[15 - p] = Sn;
                if (tl == L - 1) {
                    #pragma unroll
                    for (int j = 0; j < K_; ++j) Qc[j] = Q[(j + 15 - p) & 15];
                    Afin = A; zfin = z;
                }
                if (((p + 1) & 7) == 0) {
                    bool ok = (A0 > 1e-30f);
                    float r  = ok ? __builtin_amdgcn_rcpf(A0) : 1.0f;
                    float lz = ok ? __logf(A0) : 0.0f;
                    #pragma unroll
                    for (int q = 0; q < K_; ++q) Q[q] *= r;
                    z += lz;
                }
            }
        }
    }

    if (active) {
        float ce = cb[(size_t)e * C_ + c];
        size_t ob = ((size_t)blk * 80 + col) * 80;
        #pragma unroll
        for (int j = 0; j < K_; ++j) {
            float ratio = __expf(cb[(size_t)(e - j) * C_ + c] - ce);
            Mout[ob + j * C_ + c] = Qc[j] * ratio;
        }
        Rout[(size_t)blk * 400 + col * C_ + c] = Afin;
        if (c == 0) Zout[(size_t)blk * 80 + col] = zfin;
    }
}

// ---------------- Kernel D: in-place binary-tree matrix products ----------------
// Level l: blocks pair slots (s, s+2^l), s = i*2^(l+1), write product into slot s.
// M stored column-major: M[col*80 + row] (col = input basis index). Scales per col.
__global__ __launch_bounds__(320) void tree_kernel(
    float* __restrict__ Mst, float* __restrict__ Zst, int level, int npairs)
{
    __shared__ float Alds[6400];
    __shared__ float Blds[6400];
    __shared__ float zA[80], zB[80], ez[80], inv[80], zc[80];
    __shared__ float pm[4][80];
    __shared__ float redmax;

    int b = blockIdx.x / npairs;
    int i = blockIdx.x - b * npairs;
    int st = 1 << level;
    int s = i * (st << 1);
    const float* Ag  = Mst + ((size_t)b * NC_ + s + st) * 6400;  // later matrix
    float*       Bg  = Mst + ((size_t)b * NC_ + s) * 6400;       // earlier; also output
    float*       zBg = Zst + ((size_t)b * NC_ + s) * 80;
    const float* zAg = Zst + ((size_t)b * NC_ + s + st) * 80;
    int tid = threadIdx.x;

    #pragma unroll
    for (int k = 0; k < 20; ++k) Blds[k * 320 + tid] = Bg[k * 320 + tid];
    if (tid < 80) { zA[tid] = zAg[tid]; zB[tid] = zBg[tid]; }
    __syncthreads();
    if (tid < 64) {
        float m = zA[tid];
        if (tid < 16) m = fmaxf(m, zA[64 + tid]);
        #pragma unroll
        for (int off = 32; off; off >>= 1) m = fmaxf(m, __shfl_xor(m, off, 64));
        if (tid == 0) redmax = m;
    }
    __syncthreads();
    float maxA = redmax;
    if (tid < 80) ez[tid] = __expf(zA[tid] - maxA);
    __syncthreads();
    #pragma unroll
    for (int k = 0; k < 20; ++k) {
        int idx = k * 320 + tid;
        int mid = idx / 80;
        Alds[idx] = Ag[idx] * ez[mid];
    }
    __syncthreads();

    int col  = tid % 80;
    int rg   = tid / 80;        // 0..3
    int rowb = rg * 20;
    float acc[20];
    #pragma unroll
    for (int r = 0; r < 20; ++r) acc[r] = 0.0f;
    for (int mid = 0; mid < 80; ++mid) {
        float bv = Blds[col * 80 + mid];
        const float* arow = &Alds[mid * 80 + rowb];
        #pragma unroll
        for (int r = 0; r < 20; ++r) acc[r] = fmaf(arow[r], bv, acc[r]);
    }
    float lm = 0.0f;
    #pragma unroll
    for (int r = 0; r < 20; ++r) lm = fmaxf(lm, acc[r]);
    pm[rg][col] = lm;
    __syncthreads();
    if (tid < 80) {
        float cm = fmaxf(fmaxf(pm[0][tid], pm[1][tid]), fmaxf(pm[2][tid], pm[3][tid]));
        if (cm > 0.0f) {
            inv[tid] = 1.0f / cm;
            zc[tid]  = zB[tid] + maxA + __logf(cm);
        } else {
            inv[tid] = 0.0f;
            zc[tid]  = -3.0e38f;
        }
    }
    __syncthreads();
    float sc = inv[col];
    float4* out4 = reinterpret_cast<float4*>(Bg + col * 80 + rowb);
    #pragma unroll
    for (int r4 = 0; r4 < 5; ++r4)
        out4[r4] = make_float4(acc[r4*4+0]*sc, acc[r4*4+1]*sc, acc[r4*4+2]*sc, acc[r4*4+3]*sc);
    if (tid < 80) zBg[tid] = zc[tid];
}

// ---------------- Kernel E: final partition ----------------
__global__ __launch_bounds__(128) void final_kernel(
    const float* __restrict__ Mst, const float* __restrict__ Zst,
    const float* __restrict__ Rst, const float* __restrict__ startv,
    float* __restrict__ partition)
{
    int b = blockIdx.x;
    int tid = threadIdx.x;
    int lane = tid & 63, wv = tid >> 6;
    const float* P  = Mst + (size_t)b * NC_ * 6400;               // slot 0 product
    const float* zP = Zst + (size_t)b * NC_ * 80;
    const float* R  = Rst + ((size_t)b * NC_ + NC_ - 1) * 400;
    const float* zR = Zst + ((size_t)b * NC_ + NC_ - 1) * 80;
    __shared__ float red[2];
    __shared__ float m1s;

    if (tid == 0) {
        float m1 = -3.0e38f;
        #pragma unroll
        for (int c2 = 0; c2 < C_; ++c2) m1 = fmaxf(m1, zP[c2] + startv[c2]);
        m1s = m1;
    }
    __syncthreads();
    float m1 = m1s;

    float w = 0.0f, zi = -3.0e38f, rsum = 0.0f, zrv = 0.0f;
    if (tid < 80) {
        #pragma unroll
        for (int c2 = 0; c2 < C_; ++c2)
            w = fmaf(P[c2 * 80 + tid], __expf(zP[c2] + startv[c2] - m1), w);
        zrv = zR[tid];
        if (w > 0.0f) zi = zrv;
        rsum = (R[tid*5+0] + R[tid*5+1]) + (R[tid*5+2] + R[tid*5+3]) + R[tid*5+4];
    }
    // max of zi across 128 threads
    float m = zi;
    #pragma unroll
    for (int off = 32; off; off >>= 1) m = fmaxf(m, __shfl_xor(m, off, 64));
    if (lane == 0) red[wv] = m;
    __syncthreads();
    float m2 = fmaxf(red[0], red[1]);

    float sv = (tid < 80 && w > 0.0f) ? w * __expf(zrv - m2) * rsum : 0.0f;
    #pragma unroll
    for (int off = 32; off; off >>= 1) sv += __shfl_xor(sv, off, 64);
    if (lane == 0) red[wv] = sv;
    __syncthreads();
    if (tid == 0) partition[b] = m1 + m2 + __logf(red[0] + red[1]);
}

extern "C" void kernel_launch(void* const* d_in, const int* in_sizes, int n_in,
                              void* d_out, int out_size, void* d_ws, size_t ws_size,
                              hipStream_t stream) {
    (void)in_sizes; (void)n_in; (void)out_size; (void)ws_size;
    const float* seq    = (const float*)d_in[0];
    const int*   lens   = (const int*)  d_in[1];
    const float* W_enc  = (const float*)d_in[2];
    const float* b_enc  = (const float*)d_in[3];
    const float* W_proj = (const float*)d_in[4];
    const float* b_proj = (const float*)d_in[5];
    const float* trans  = (const float*)d_in[6];
    const float* startv = (const float*)d_in[7];
    const float* dur    = (const float*)d_in[8];

    float* out       = (float*)d_out;
    float* partition = out;
    float* cum       = out + B_;

    float* emit = (float*)d_ws;                       // B*C*T
    float* Mst  = emit + (size_t)B_ * C_ * T_;        // B*NC*80*80
    float* Rst  = Mst  + (size_t)B_ * NC_ * 6400;     // B*NC*80*5
    float* Zst  = Rst  + (size_t)B_ * NC_ * 400;      // B*NC*80

    encoder_kernel<<<(B_ * T_) / 256, 256, 0, stream>>>(seq, W_enc, b_enc, W_proj, b_proj, emit);
    cumsum_kernel<<<B_ * C_, 256, 0, stream>>>(emit, cum);
    chunk_kernel<<<B_ * NC_, 448, 0, stream>>>(emit, cum, lens, trans, dur, Mst, Rst, Zst);
    tree_kernel<<<B_ * 15, 320, 0, stream>>>(Mst, Zst, 0, 15);
    tree_kernel<<<B_ * 8,  320, 0, stream>>>(Mst, Zst, 1, 8);
    tree_kernel<<<B_ * 4,  320, 0, stream>>>(Mst, Zst, 2, 4);
    tree_kernel<<<B_ * 2,  320, 0, stream>>>(Mst, Zst, 3, 2);
    tree_kernel<<<B_ * 1,  320, 0, stream>>>(Mst, Zst, 4, 1);
    final_kernel<<<B_, 128, 0, stream>>>(Mst, Zst, Rst, startv, partition);
}

// Round 4
// 142.580 us; speedup vs baseline: 7.6166x; 1.3884x over previous
//
#include <hip/hip_runtime.h>
#include <hip/hip_bf16.h>

#define B_ 8
#define T_ 8192
#define DNA_ 4
#define HID_ 256
#define C_ 5
#define K_ 16
#define NC_ 32   // chunks per batch for the parallel scan

__device__ __forceinline__ float gelu_tanh(float x) {
    float u = 0.7978845608028654f * (x + 0.044715f * x * x * x);
    float e = __expf(2.0f * u);
    float th = 1.0f - 2.0f / (e + 1.0f);
    return 0.5f * x * (1.0f + th);
}

// ---------------- Kernel A: encoder (hidden-dim split) -> emitA/emitB [b][c][t] ----------------
__global__ __launch_bounds__(256) void encoder_kernel(
    const float* __restrict__ seq, const float* __restrict__ W_enc,
    const float* __restrict__ b_enc, const float* __restrict__ W_proj,
    const float* __restrict__ b_proj, float* __restrict__ emitA,
    float* __restrict__ emitB)
{
    __shared__ float4 we[128];
    __shared__ float  be[128];
    __shared__ float  wp[128 * C_];
    int tid = threadIdx.x;
    int half = blockIdx.x >> 8;      // 0 or 1: which 128 of the 256 hidden units
    int blk  = blockIdx.x & 255;
    int h0 = half * 128;
    if (tid < 128) {
        int h = h0 + tid;
        we[tid] = make_float4(W_enc[0*HID_+h], W_enc[1*HID_+h], W_enc[2*HID_+h], W_enc[3*HID_+h]);
        be[tid] = b_enc[h];
    }
    for (int i = tid; i < 128 * C_; i += 256) wp[i] = W_proj[h0 * C_ + i];
    __syncthreads();
    int gid = blk * 256 + tid;
    int b = gid >> 13;
    int t = gid & (T_ - 1);
    float4 s = reinterpret_cast<const float4*>(seq)[(size_t)b * T_ + t];
    float a0, a1, a2, a3, a4;
    if (half == 0) { a0 = b_proj[0]; a1 = b_proj[1]; a2 = b_proj[2]; a3 = b_proj[3]; a4 = b_proj[4]; }
    else           { a0 = a1 = a2 = a3 = a4 = 0.0f; }
    #pragma unroll 8
    for (int h = 0; h < 128; ++h) {
        float4 w = we[h];
        float pre = be[h] + s.x*w.x + s.y*w.y + s.z*w.z + s.w*w.w;
        float hd = gelu_tanh(pre);
        a0 = fmaf(hd, wp[h*C_+0], a0);
        a1 = fmaf(hd, wp[h*C_+1], a1);
        a2 = fmaf(hd, wp[h*C_+2], a2);
        a3 = fmaf(hd, wp[h*C_+3], a3);
        a4 = fmaf(hd, wp[h*C_+4], a4);
    }
    float* em = half ? emitB : emitA;
    size_t base = (size_t)b * C_ * T_ + t;
    em[base + 0*T_] = a0;
    em[base + 1*T_] = a1;
    em[base + 2*T_] = a2;
    em[base + 3*T_] = a3;
    em[base + 4*T_] = a4;
}

// ---------------- Kernel B: cumsum, block per batch, wave per class ----------------
__global__ __launch_bounds__(320) void cumsum_kernel(
    const float* __restrict__ emitA, const float* __restrict__ emitB,
    float* __restrict__ cum)
{
    __shared__ float stage[C_][260];   // padded: bank stride 4 per class
    int b = blockIdx.x;
    int tid = threadIdx.x;
    int lane = tid & 63, c = tid >> 6;  // wave = class
    const float4* eA4 = reinterpret_cast<const float4*>(emitA + ((size_t)b * C_ + c) * T_);
    const float4* eB4 = reinterpret_cast<const float4*>(emitB + ((size_t)b * C_ + c) * T_);
    float* cb = cum + (size_t)b * (T_ + 1) * C_;
    if (tid < C_) cb[tid] = 0.0f;
    float carry = 0.0f;
    for (int it = 0; it < 32; ++it) {
        int idx = it * 64 + lane;
        float4 fa = eA4[idx], fb = eB4[idx];
        float v0 = fa.x + fb.x, v1 = fa.y + fb.y, v2 = fa.z + fb.z, v3 = fa.w + fb.w;
        float tsum = (v0 + v1) + (v2 + v3);
        float si = tsum;
        #pragma unroll
        for (int off = 1; off < 64; off <<= 1) {
            float n = __shfl_up(si, off, 64);
            if (lane >= off) si += n;
        }
        float excl = si - tsum + carry;
        float p0 = excl + v0, p1 = p0 + v1, p2 = p1 + v2, p3 = p2 + v3;
        *reinterpret_cast<float4*>(&stage[c][lane * 4]) = make_float4(p0, p1, p2, p3);
        carry += __shfl(si, 63, 64);
        __syncthreads();
        float* dst = cb + ((size_t)(it * 256) + 1) * C_;
        for (int i = tid; i < 1280; i += 320) {
            int tt = i / 5, cc = i - tt * 5;
            dst[i] = stage[cc][tt];
        }
        __syncthreads();
    }
}

// ---------------- Kernel C: per-chunk 80x80 transfer matrices (running-product form) ----------------
#define CHUNK_STEP(PP, TL)                                                    \
    {                                                                         \
        float g  = g_lds[c][(TL)];                                            \
        float gi = gi_lds[c][(TL)];                                           \
        P *= g; invP *= gi;                                                   \
        float d0 = 0.f, d1 = 0.f, d2 = 0.f, d3 = 0.f;                         \
        d0 = fmaf(W[0],  ed[(0  + (PP)) & 15], d0);                           \
        d1 = fmaf(W[1],  ed[(1  + (PP)) & 15], d1);                           \
        d2 = fmaf(W[2],  ed[(2  + (PP)) & 15], d2);                           \
        d3 = fmaf(W[3],  ed[(3  + (PP)) & 15], d3);                           \
        d0 = fmaf(W[4],  ed[(4  + (PP)) & 15], d0);                           \
        d1 = fmaf(W[5],  ed[(5  + (PP)) & 15], d1);                           \
        d2 = fmaf(W[6],  ed[(6  + (PP)) & 15], d2);                           \
        d3 = fmaf(W[7],  ed[(7  + (PP)) & 15], d3);                           \
        d0 = fmaf(W[8],  ed[(8  + (PP)) & 15], d0);                           \
        d1 = fmaf(W[9],  ed[(9  + (PP)) & 15], d1);                           \
        d2 = fmaf(W[10], ed[(10 + (PP)) & 15], d2);                           \
        d3 = fmaf(W[11], ed[(11 + (PP)) & 15], d3);                           \
        d0 = fmaf(W[12], ed[(12 + (PP)) & 15], d0);                           \
        d1 = fmaf(W[13], ed[(13 + (PP)) & 15], d1);                           \
        d2 = fmaf(W[14], ed[(14 + (PP)) & 15], d2);                           \
        d3 = fmaf(W[15], ed[(15 + (PP)) & 15], d3);                           \
        float dotv = (d0 + d1) + (d2 + d3);                                   \
        astep = P * dotv;                                                     \
        float A0 = __shfl(astep, base5 + 0, 64);                              \
        float A1 = __shfl(astep, base5 + 1, 64);                              \
        float A2 = __shfl(astep, base5 + 2, 64);                              \
        float A3 = __shfl(astep, base5 + 3, 64);                              \
        float A4 = __shfl(astep, base5 + 4, 64);                              \
        A0v = A0;                                                             \
        float Sn = fmaf(eT[0], A0, fmaf(eT[1], A1, fmaf(eT[2], A2,           \
                   fmaf(eT[3], A3, eT[4] * A4))));                            \
        W[15 - (PP)] = Sn * invP;                                             \
    }

#define CHUNK_RENORM()                                                        \
    {                                                                         \
        bool ok = (A0v > 1e-30f);                                             \
        float r  = ok ? __builtin_amdgcn_rcpf(A0v) : 1.0f;                    \
        float lz = ok ? __logf(A0v) : 0.0f;                                   \
        float f = P * r;                                                      \
        _Pragma("unroll") for (int q = 0; q < 16; ++q) W[q] *= f;             \
        P = 1.0f; invP = 1.0f; z += lz;                                       \
    }

__global__ __launch_bounds__(448) void chunk_kernel(
    const float* __restrict__ emitA, const float* __restrict__ emitB,
    const float* __restrict__ cum, const int* __restrict__ lengths,
    const float* __restrict__ trans, const float* __restrict__ dur,
    __hip_bfloat16* __restrict__ Mout, float* __restrict__ Rout,
    float* __restrict__ Zout)
{
    __shared__ float g_lds[C_][260];
    __shared__ float gi_lds[C_][260];
    int blk = blockIdx.x;
    int b = blk >> 5, k = blk & (NC_ - 1);
    int len = lengths[b];
    int s = (k * len) >> 5;
    int e = ((k + 1) * len) >> 5;
    int L = e - s;                       // 128..256
    int tid = threadIdx.x;

    if (tid < L) {
        #pragma unroll
        for (int cc = 0; cc < C_; ++cc) {
            size_t gi_ = ((size_t)b * C_ + cc) * T_ + s + tid;
            float ev = emitA[gi_] + emitB[gi_];
            g_lds[cc][tid]  = __expf(ev);
            gi_lds[cc][tid] = __expf(-ev);
        }
    }
    __syncthreads();

    int lane = tid & 63, wv = tid >> 6;
    int cin = lane / 5;                  // 0..12
    int c = lane - cin * 5;
    int col = wv * 12 + cin;
    bool active = (cin < 12) && (col < 80);
    int base5 = (cin < 12) ? (cin * 5) : 0;

    const float* cb = cum + (size_t)b * (T_ + 1) * C_;

    float ed[K_], eT[C_];
    #pragma unroll
    for (int j = 0; j < K_; ++j) ed[j] = __expf(dur[c * K_ + j]);
    #pragma unroll
    for (int cc = 0; cc < C_; ++cc) eT[cc] = __expf(trans[cc * C_ + c]);

    float W[K_];
    #pragma unroll
    for (int j = 0; j < K_; ++j) W[j] = 0.0f;
    {
        int j0 = col / 5;
        int c0 = col - j0 * 5;
        if (active && c == c0) {
            int i1 = s - j0; if (i1 < 0) i1 = 0;
            float val = __expf(cb[(size_t)s * C_ + c] - cb[(size_t)i1 * C_ + c]);
            #pragma unroll
            for (int j = 0; j < K_; ++j) if (j == j0) W[j] = val;
        }
    }

    float P = 1.0f, invP = 1.0f, z = 0.0f, Afin = 0.0f;
    float astep = 0.0f, A0v = 0.0f;
    int nfull = (L - 1) >> 4;            // full 16-step blocks before the final block
    int rem = L - (nfull << 4);          // 1..16 steps in final block
    int tl0 = 0;

    for (int bi = 0; bi < nfull; ++bi) {
        #pragma unroll
        for (int p = 0; p < 16; ++p) {
            CHUNK_STEP(p, tl0 + p);
            if ((p & 7) == 7) CHUNK_RENORM();
        }
        tl0 += 16;
    }
    {
        #pragma unroll
        for (int p = 0; p < 16; ++p) {
            if (p < rem) {
                CHUNK_STEP(p, tl0 + p);
                if (p == rem - 1) Afin = astep;
                if (((p & 7) == 7) && (p < rem - 1)) CHUNK_RENORM();
            }
        }
    }

    if (active) {
        int pn = L & 15;
        float ce = cb[(size_t)e * C_ + c];
        size_t ob = ((size_t)blk * 80 + col) * 80;
        if (k < NC_ - 1) {               // last chunk's M is never used
            #pragma unroll
            for (int slot = 0; slot < 16; ++slot) {
                int j = (slot + pn) & 15;
                float ratio = __expf(cb[(size_t)(e - j) * C_ + c] - ce);
                Mout[ob + j * C_ + c] = __float2bfloat16(W[slot] * P * ratio);
            }
        }
        Rout[(size_t)blk * 400 + col * C_ + c] = Afin;
        if (c == 0) Zout[(size_t)blk * 80 + col] = z;
    }
}

// ---------------- Kernel D: in-place binary-tree matrix products (bf16 M) ----------------
// Level l pairs slots (s, s+2^l), s = i*2^(l+1); product of chain M[0..NC-2] only.
__global__ __launch_bounds__(320) void tree_kernel(
    __hip_bfloat16* __restrict__ Mst, float* __restrict__ Zst, int level, int npairs)
{
    __shared__ float Alds[80 * 84];   // [mid][row], pad 84
    __shared__ float Blds[80 * 82];   // [mid][col], pad 82
    __shared__ float zA[80], zB[80], ez[80], inv[80], zc[80];
    __shared__ float pm[8][80];
    __shared__ float redmax;

    int bb = blockIdx.x / npairs;
    int i = blockIdx.x - bb * npairs;
    int st = 1 << level;
    int sl = i * (st << 1);
    const __hip_bfloat16* Ag = Mst + ((size_t)bb * NC_ + sl + st) * 6400;
    __hip_bfloat16*       Bg = Mst + ((size_t)bb * NC_ + sl) * 6400;
    float* zBg = Zst + ((size_t)bb * NC_ + sl) * 80;
    const float* zAg = Zst + ((size_t)bb * NC_ + sl + st) * 80;
    int tid = threadIdx.x;

    if (tid < 80) { zA[tid] = zAg[tid]; zB[tid] = zBg[tid]; }
    #pragma unroll
    for (int kk = 0; kk < 20; ++kk) {
        int idx = kk * 320 + tid;
        int colB = idx / 80, mid = idx - colB * 80;
        Blds[mid * 82 + colB] = __bfloat162float(Bg[idx]);
    }
    __syncthreads();
    if (tid < 64) {
        float m = zA[tid];
        if (tid < 16) m = fmaxf(m, zA[64 + tid]);
        #pragma unroll
        for (int off = 32; off; off >>= 1) m = fmaxf(m, __shfl_xor(m, off, 64));
        if (tid == 0) redmax = m;
    }
    __syncthreads();
    float maxA = redmax;
    if (tid < 80) ez[tid] = __expf(zA[tid] - maxA);
    __syncthreads();
    #pragma unroll
    for (int kk = 0; kk < 20; ++kk) {
        int idx = kk * 320 + tid;
        int mid = idx / 80, row = idx - mid * 80;
        Alds[mid * 84 + row] = __bfloat162float(Ag[idx]) * ez[mid];
    }
    __syncthreads();

    int cg = tid % 40, rg = tid / 40;    // cols 2cg,2cg+1; rows rg*10..+9
    int col0 = cg * 2, rowb = rg * 10;
    float acc0[10], acc1[10];
    #pragma unroll
    for (int r = 0; r < 10; ++r) { acc0[r] = 0.0f; acc1[r] = 0.0f; }
    for (int mid = 0; mid < 80; ++mid) {
        float2 bv = *reinterpret_cast<float2*>(&Blds[mid * 82 + col0]);
        const float2* ap = reinterpret_cast<const float2*>(&Alds[mid * 84 + rowb]);
        #pragma unroll
        for (int r2 = 0; r2 < 5; ++r2) {
            float2 av = ap[r2];
            acc0[r2*2+0] = fmaf(av.x, bv.x, acc0[r2*2+0]);
            acc0[r2*2+1] = fmaf(av.y, bv.x, acc0[r2*2+1]);
            acc1[r2*2+0] = fmaf(av.x, bv.y, acc1[r2*2+0]);
            acc1[r2*2+1] = fmaf(av.y, bv.y, acc1[r2*2+1]);
        }
    }
    float lm0 = 0.0f, lm1 = 0.0f;
    #pragma unroll
    for (int r = 0; r < 10; ++r) { lm0 = fmaxf(lm0, acc0[r]); lm1 = fmaxf(lm1, acc1[r]); }
    *reinterpret_cast<float2*>(&pm[rg][col0]) = make_float2(lm0, lm1);
    __syncthreads();
    if (tid < 80) {
        float cm = 0.0f;
        #pragma unroll
        for (int r = 0; r < 8; ++r) cm = fmaxf(cm, pm[r][tid]);
        if (cm > 0.0f) { inv[tid] = 1.0f / cm; zc[tid] = zB[tid] + maxA + __logf(cm); }
        else           { inv[tid] = 0.0f;      zc[tid] = -3.0e38f; }
    }
    __syncthreads();
    float s0 = inv[col0], s1 = inv[col0 + 1];
    #pragma unroll
    for (int r = 0; r < 10; ++r) Bg[col0 * 80 + rowb + r] = __float2bfloat16(acc0[r] * s0);
    #pragma unroll
    for (int r = 0; r < 10; ++r) Bg[(col0 + 1) * 80 + rowb + r] = __float2bfloat16(acc1[r] * s1);
    if (tid < 80) zBg[tid] = zc[tid];
}

// ---------------- Kernel E: final partition ----------------
__global__ __launch_bounds__(128) void final_kernel(
    const __hip_bfloat16* __restrict__ Mst, const float* __restrict__ Zst,
    const float* __restrict__ Rst, const float* __restrict__ startv,
    float* __restrict__ partition)
{
    int b = blockIdx.x;
    int tid = threadIdx.x;
    int lane = tid & 63, wv = tid >> 6;
    const __hip_bfloat16* P = Mst + (size_t)b * NC_ * 6400;   // slot 0 = product of M[0..NC-2]
    const float* zP = Zst + (size_t)b * NC_ * 80;
    const float* R  = Rst + ((size_t)b * NC_ + NC_ - 1) * 400;
    const float* zR = Zst + ((size_t)b * NC_ + NC_ - 1) * 80;
    __shared__ float red[2];
    __shared__ float m1s;

    if (tid == 0) {
        float m1 = -3.0e38f;
        #pragma unroll
        for (int c2 = 0; c2 < C_; ++c2) m1 = fmaxf(m1, zP[c2] + startv[c2]);
        m1s = m1;
    }
    __syncthreads();
    float m1 = m1s;

    float w = 0.0f, zi = -3.0e38f, rsum = 0.0f, zrv = 0.0f;
    if (tid < 80) {
        #pragma unroll
        for (int c2 = 0; c2 < C_; ++c2)
            w = fmaf(__bfloat162float(P[c2 * 80 + tid]), __expf(zP[c2] + startv[c2] - m1), w);
        zrv = zR[tid];
        if (w > 0.0f) zi = zrv;
        rsum = (R[tid*5+0] + R[tid*5+1]) + (R[tid*5+2] + R[tid*5+3]) + R[tid*5+4];
    }
    float m = zi;
    #pragma unroll
    for (int off = 32; off; off >>= 1) m = fmaxf(m, __shfl_xor(m, off, 64));
    if (lane == 0) red[wv] = m;
    __syncthreads();
    float m2 = fmaxf(red[0], red[1]);

    float sv = (tid < 80 && w > 0.0f) ? w * __expf(zrv - m2) * rsum : 0.0f;
    #pragma unroll
    for (int off = 32; off; off >>= 1) sv += __shfl_xor(sv, off, 64);
    if (lane == 0) red[wv] = sv;
    __syncthreads();
    if (tid == 0) partition[b] = m1 + m2 + __logf(red[0] + red[1]);
}

extern "C" void kernel_launch(void* const* d_in, const int* in_sizes, int n_in,
                              void* d_out, int out_size, void* d_ws, size_t ws_size,
                              hipStream_t stream) {
    (void)in_sizes; (void)n_in; (void)out_size; (void)ws_size;
    const float* seq    = (const float*)d_in[0];
    const int*   lens   = (const int*)  d_in[1];
    const float* W_enc  = (const float*)d_in[2];
    const float* b_enc  = (const float*)d_in[3];
    const float* W_proj = (const float*)d_in[4];
    const float* b_proj = (const float*)d_in[5];
    const float* trans  = (const float*)d_in[6];
    const float* startv = (const float*)d_in[7];
    const float* dur    = (const float*)d_in[8];

    float* out       = (float*)d_out;
    float* partition = out;
    float* cum       = out + B_;

    float* emitA = (float*)d_ws;                              // B*C*T floats
    float* emitB = emitA + (size_t)B_ * C_ * T_;              // B*C*T floats
    __hip_bfloat16* Mst = (__hip_bfloat16*)(emitB + (size_t)B_ * C_ * T_);  // B*NC*6400 bf16
    float* Rst = (float*)(Mst + (size_t)B_ * NC_ * 6400);     // B*NC*400 floats
    float* Zst = Rst + (size_t)B_ * NC_ * 400;                // B*NC*80 floats

    encoder_kernel<<<512, 256, 0, stream>>>(seq, W_enc, b_enc, W_proj, b_proj, emitA, emitB);
    cumsum_kernel<<<B_, 320, 0, stream>>>(emitA, emitB, cum);
    chunk_kernel<<<B_ * NC_, 448, 0, stream>>>(emitA, emitB, cum, lens, trans, dur, Mst, Rst, Zst);
    tree_kernel<<<B_ * 15, 320, 0, stream>>>(Mst, Zst, 0, 15);
    tree_kernel<<<B_ * 8,  320, 0, stream>>>(Mst, Zst, 1, 8);
    tree_kernel<<<B_ * 4,  320, 0, stream>>>(Mst, Zst, 2, 4);
    tree_kernel<<<B_ * 2,  320, 0, stream>>>(Mst, Zst, 3, 2);
    tree_kernel<<<B_ * 1,  320, 0, stream>>>(Mst, Zst, 4, 1);
    final_kernel<<<B_, 128, 0, stream>>>(Mst, Zst, Rst, startv, partition);
}

// Round 5
// 140.444 us; speedup vs baseline: 7.7325x; 1.0152x over previous
//
#include <hip/hip_runtime.h>
#include <hip/hip_bf16.h>

#define B_ 8
#define T_ 8192
#define HID_ 256
#define C_ 5
#define K_ 16
#define NC_ 64    // chunks per batch
#define NTILE 32  // 256-position tiles per batch (cumsum pipeline)
#define GSPAN 144 // 16 pre-window + up to 128 in-window g values

__device__ __forceinline__ float gelu_tanh(float x) {
    float u = 0.7978845608028654f * (x + 0.044715f * x * x * x);
    float e = __expf(2.0f * u);
    float th = 1.0f - 2.0f / (e + 1.0f);
    return 0.5f * x * (1.0f + th);
}

// ---------------- Kernel A: encoder (hidden split) -> emitA/emitB + per-tile class sums ----------------
__global__ __launch_bounds__(256) void encoder_kernel(
    const float* __restrict__ seq, const float* __restrict__ W_enc,
    const float* __restrict__ b_enc, const float* __restrict__ W_proj,
    const float* __restrict__ b_proj, float* __restrict__ emitA,
    float* __restrict__ emitB, float* __restrict__ PA)
{
    __shared__ float4 we[128];
    __shared__ float  be[128];
    __shared__ float  wp[128 * C_];
    __shared__ float  prd[4][C_];
    int tid = threadIdx.x;
    int half = blockIdx.x >> 8;
    int blk  = blockIdx.x & 255;
    int h0 = half * 128;
    if (tid < 128) {
        int h = h0 + tid;
        we[tid] = make_float4(W_enc[0*HID_+h], W_enc[1*HID_+h], W_enc[2*HID_+h], W_enc[3*HID_+h]);
        be[tid] = b_enc[h];
    }
    for (int i = tid; i < 128 * C_; i += 256) wp[i] = W_proj[h0 * C_ + i];
    __syncthreads();
    int b = blk >> 5;              // 32 blocks (tiles) per batch
    int tile = blk & 31;
    int t = tile * 256 + tid;
    float4 s = reinterpret_cast<const float4*>(seq)[(size_t)b * T_ + t];
    float a0, a1, a2, a3, a4;
    if (half == 0) { a0 = b_proj[0]; a1 = b_proj[1]; a2 = b_proj[2]; a3 = b_proj[3]; a4 = b_proj[4]; }
    else           { a0 = a1 = a2 = a3 = a4 = 0.0f; }
    #pragma unroll 8
    for (int h = 0; h < 128; ++h) {
        float4 w = we[h];
        float pre = be[h] + s.x*w.x + s.y*w.y + s.z*w.z + s.w*w.w;
        float hd = gelu_tanh(pre);
        a0 = fmaf(hd, wp[h*C_+0], a0);
        a1 = fmaf(hd, wp[h*C_+1], a1);
        a2 = fmaf(hd, wp[h*C_+2], a2);
        a3 = fmaf(hd, wp[h*C_+3], a3);
        a4 = fmaf(hd, wp[h*C_+4], a4);
    }
    float* em = half ? emitB : emitA;
    size_t base = (size_t)b * C_ * T_ + t;
    em[base + 0*T_] = a0;
    em[base + 1*T_] = a1;
    em[base + 2*T_] = a2;
    em[base + 3*T_] = a3;
    em[base + 4*T_] = a4;
    // per-tile class sums for the cumsum pipeline
    float s0 = a0, s1 = a1, s2 = a2, s3 = a3, s4 = a4;
    #pragma unroll
    for (int off = 1; off < 64; off <<= 1) {
        s0 += __shfl_xor(s0, off, 64);
        s1 += __shfl_xor(s1, off, 64);
        s2 += __shfl_xor(s2, off, 64);
        s3 += __shfl_xor(s3, off, 64);
        s4 += __shfl_xor(s4, off, 64);
    }
    int lane = tid & 63, wv = tid >> 6;
    if (lane == 0) { prd[wv][0]=s0; prd[wv][1]=s1; prd[wv][2]=s2; prd[wv][3]=s3; prd[wv][4]=s4; }
    __syncthreads();
    if (tid < C_) {
        float t4 = (prd[0][tid] + prd[1][tid]) + (prd[2][tid] + prd[3][tid]);
        PA[((half * B_ + b) * NTILE + tile) * C_ + tid] = t4;
    }
}

// ---------------- Kernel B: cum writer (one block per (b,c,tile)) ----------------
__global__ __launch_bounds__(64) void cumwrite_kernel(
    const float* __restrict__ emitA, const float* __restrict__ emitB,
    const float* __restrict__ PA, float* __restrict__ cum)
{
    int bx = blockIdx.x;
    int tile = bx & (NTILE - 1);
    int bc = bx >> 5;               // 0..39
    int b = bc / C_, c = bc - b * C_;
    int lane = threadIdx.x;
    float off = 0.0f;
    for (int tt = 0; tt < tile; ++tt)
        off += PA[((0 * B_ + b) * NTILE + tt) * C_ + c]
             + PA[((1 * B_ + b) * NTILE + tt) * C_ + c];
    const float* eA = emitA + ((size_t)b * C_ + c) * T_;
    const float* eB = emitB + ((size_t)b * C_ + c) * T_;
    float* cb = cum + (size_t)b * (T_ + 1) * C_;
    if (tile == 0 && lane == 0) cb[c] = 0.0f;
    float carry = off;
    #pragma unroll
    for (int i = 0; i < 4; ++i) {
        int idx = tile * 256 + i * 64 + lane;
        float v = eA[idx] + eB[idx];
        float si = v;
        #pragma unroll
        for (int o = 1; o < 64; o <<= 1) {
            float n = __shfl_up(si, o, 64);
            if (lane >= o) si += n;
        }
        cb[(size_t)(idx + 1) * C_ + c] = carry + si;
        carry += __shfl(si, 63, 64);
    }
}

// ---------------- Kernel C: per-chunk 80x80 transfer matrices ----------------
#define CHUNK_STEP(PP, TL)                                                    \
    {                                                                         \
        P *= g_lds[c][16 + (TL)];                                             \
        float invP = __builtin_amdgcn_rcpf(P);                                \
        float d0 = 0.f, d1 = 0.f, d2 = 0.f, d3 = 0.f;                         \
        d0 = fmaf(W[0],  ed[(0  + (PP)) & 15], d0);                           \
        d1 = fmaf(W[1],  ed[(1  + (PP)) & 15], d1);                           \
        d2 = fmaf(W[2],  ed[(2  + (PP)) & 15], d2);                           \
        d3 = fmaf(W[3],  ed[(3  + (PP)) & 15], d3);                           \
        d0 = fmaf(W[4],  ed[(4  + (PP)) & 15], d0);                           \
        d1 = fmaf(W[5],  ed[(5  + (PP)) & 15], d1);                           \
        d2 = fmaf(W[6],  ed[(6  + (PP)) & 15], d2);                           \
        d3 = fmaf(W[7],  ed[(7  + (PP)) & 15], d3);                           \
        d0 = fmaf(W[8],  ed[(8  + (PP)) & 15], d0);                           \
        d1 = fmaf(W[9],  ed[(9  + (PP)) & 15], d1);                           \
        d2 = fmaf(W[10], ed[(10 + (PP)) & 15], d2);                           \
        d3 = fmaf(W[11], ed[(11 + (PP)) & 15], d3);                           \
        d0 = fmaf(W[12], ed[(12 + (PP)) & 15], d0);                           \
        d1 = fmaf(W[13], ed[(13 + (PP)) & 15], d1);                           \
        d2 = fmaf(W[14], ed[(14 + (PP)) & 15], d2);                           \
        d3 = fmaf(W[15], ed[(15 + (PP)) & 15], d3);                           \
        float dotv = (d0 + d1) + (d2 + d3);                                   \
        astep = P * dotv;                                                     \
        float A0 = __shfl(astep, base5 + 0, 64);                              \
        float A1 = __shfl(astep, base5 + 1, 64);                              \
        float A2 = __shfl(astep, base5 + 2, 64);                              \
        float A3 = __shfl(astep, base5 + 3, 64);                              \
        float A4 = __shfl(astep, base5 + 4, 64);                              \
        A0v = A0;                                                             \
        float Sn = fmaf(eT[0], A0, fmaf(eT[1], A1, fmaf(eT[2], A2,           \
                   fmaf(eT[3], A3, eT[4] * A4))));                            \
        W[15 - (PP)] = Sn * invP;                                             \
    }

#define CHUNK_RENORM()                                                        \
    {                                                                         \
        bool ok = (A0v > 1e-30f);                                             \
        float r  = ok ? __builtin_amdgcn_rcpf(A0v) : 1.0f;                    \
        float lz = ok ? __logf(A0v) : 0.0f;                                   \
        float f = P * r;                                                      \
        _Pragma("unroll") for (int q = 0; q < 16; ++q) W[q] *= f;             \
        P = 1.0f; z += lz;                                                    \
    }

__global__ __launch_bounds__(448) void chunk_kernel(
    const float* __restrict__ emitA, const float* __restrict__ emitB,
    const int* __restrict__ lengths, const float* __restrict__ trans,
    const float* __restrict__ dur, __hip_bfloat16* __restrict__ Mout,
    float* __restrict__ Rout, float* __restrict__ Zout)
{
    __shared__ float g_lds[C_][GSPAN + 4];
    int blk = blockIdx.x;
    int b = blk >> 6, k = blk & (NC_ - 1);
    int len = lengths[b];
    int s = (k * len) >> 6;
    int e = ((k + 1) * len) >> 6;
    int L = e - s;                       // 64..128
    int tid = threadIdx.x;

    for (int i = tid; i < C_ * GSPAN; i += 448) {
        int cc = i / GSPAN, j = i - cc * GSPAN;
        int pos = s - 16 + j;
        float val = 1.0f;
        if (pos >= 0 && j < 16 + L) {
            size_t gidx = ((size_t)b * C_ + cc) * T_ + pos;
            val = __expf(emitA[gidx] + emitB[gidx]);
        }
        g_lds[cc][j] = val;
    }
    __syncthreads();

    int lane = tid & 63, wv = tid >> 6;
    int cin = lane / 5;                  // 0..12
    int c = lane - cin * 5;
    int col = wv * 12 + cin;
    bool active = (cin < 12) && (col < 80);
    int base5 = (cin < 12) ? (cin * 5) : 0;

    float ed[K_], eT[C_];
    #pragma unroll
    for (int j = 0; j < K_; ++j) ed[j] = __expf(dur[c * K_ + j]);
    #pragma unroll
    for (int cc = 0; cc < C_; ++cc) eT[cc] = __expf(trans[cc * C_ + c]);

    float W[K_];
    #pragma unroll
    for (int j = 0; j < K_; ++j) W[j] = 0.0f;
    if (active) {
        int j0 = col / 5;
        int c0 = col - j0 * 5;
        if (c == c0) {
            float v = 1.0f;
            for (int j = 16 - j0; j < 16; ++j) v *= g_lds[c][j];
            #pragma unroll
            for (int j = 0; j < K_; ++j) if (j == j0) W[j] = v;
        }
    }

    float P = 1.0f, z = 0.0f, Afin = 0.0f, astep = 0.0f, A0v = 0.0f;
    int nfull = (L - 1) >> 4;            // 3..7
    int rem = L - (nfull << 4);          // 1..16
    int tl0 = 0;

    for (int bi = 0; bi < nfull; ++bi) {
        #pragma unroll
        for (int p = 0; p < 16; ++p) CHUNK_STEP(p, tl0 + p);
        CHUNK_RENORM();
        tl0 += 16;
    }
    #pragma unroll
    for (int p = 0; p < 16; ++p) {
        if (p < rem) {
            CHUNK_STEP(p, tl0 + p);
            if (p == rem - 1) Afin = astep;
        }
    }

    if (active) {
        int pn = L & 15;
        size_t ob = ((size_t)blk * 80 + col) * 80;
        if (k < NC_ - 1) {               // last chunk's M never used
            #pragma unroll
            for (int slot = 0; slot < 16; ++slot) {
                int j = (slot + pn) & 15;
                float pr = 1.0f;
                for (int i2 = L - j; i2 < L; ++i2) pr *= g_lds[c][16 + i2];
                Mout[ob + j * C_ + c] =
                    __float2bfloat16(W[slot] * P * __builtin_amdgcn_rcpf(pr));
            }
        }
        Rout[(size_t)blk * 400 + col * C_ + c] = Afin;
        if (c == 0) Zout[(size_t)blk * 80 + col] = z;
    }
}

// ---------------- Kernel D: in-place binary-tree matrix products (bf16 M) ----------------
__global__ __launch_bounds__(320) void tree_kernel(
    __hip_bfloat16* __restrict__ Mst, float* __restrict__ Zst, int level, int npairs)
{
    __shared__ float Alds[80 * 84];   // [mid][row], pad 84
    __shared__ float Blds[80 * 82];   // [mid][col], pad 82
    __shared__ float zA[80], zB[80], ez[80], inv[80], zc[80];
    __shared__ float pm[8][80];
    __shared__ float redmax;

    int bb = blockIdx.x / npairs;
    int i = blockIdx.x - bb * npairs;
    int st = 1 << level;
    int sl = i * (st << 1);
    const __hip_bfloat16* Ag = Mst + ((size_t)bb * NC_ + sl + st) * 6400;
    __hip_bfloat16*       Bg = Mst + ((size_t)bb * NC_ + sl) * 6400;
    float* zBg = Zst + ((size_t)bb * NC_ + sl) * 80;
    const float* zAg = Zst + ((size_t)bb * NC_ + sl + st) * 80;
    int tid = threadIdx.x;

    if (tid < 80) { zA[tid] = zAg[tid]; zB[tid] = zBg[tid]; }
    #pragma unroll
    for (int kk = 0; kk < 20; ++kk) {
        int idx = kk * 320 + tid;
        int colB = idx / 80, mid = idx - colB * 80;
        Blds[mid * 82 + colB] = __bfloat162float(Bg[idx]);
    }
    __syncthreads();
    if (tid < 64) {
        float m = zA[tid];
        if (tid < 16) m = fmaxf(m, zA[64 + tid]);
        #pragma unroll
        for (int off = 32; off; off >>= 1) m = fmaxf(m, __shfl_xor(m, off, 64));
        if (tid == 0) redmax = m;
    }
    __syncthreads();
    float maxA = redmax;
    if (tid < 80) ez[tid] = __expf(zA[tid] - maxA);
    __syncthreads();
    #pragma unroll
    for (int kk = 0; kk < 20; ++kk) {
        int idx = kk * 320 + tid;
        int mid = idx / 80, row = idx - mid * 80;
        Alds[mid * 84 + row] = __bfloat162float(Ag[idx]) * ez[mid];
    }
    __syncthreads();

    int cg = tid % 40, rg = tid / 40;    // cols 2cg,2cg+1; rows rg*10..+9
    int col0 = cg * 2, rowb = rg * 10;
    float acc0[10], acc1[10];
    #pragma unroll
    for (int r = 0; r < 10; ++r) { acc0[r] = 0.0f; acc1[r] = 0.0f; }
    for (int mid = 0; mid < 80; ++mid) {
        float2 bv = *reinterpret_cast<float2*>(&Blds[mid * 82 + col0]);
        const float2* ap = reinterpret_cast<const float2*>(&Alds[mid * 84 + rowb]);
        #pragma unroll
        for (int r2 = 0; r2 < 5; ++r2) {
            float2 av = ap[r2];
            acc0[r2*2+0] = fmaf(av.x, bv.x, acc0[r2*2+0]);
            acc0[r2*2+1] = fmaf(av.y, bv.x, acc0[r2*2+1]);
            acc1[r2*2+0] = fmaf(av.x, bv.y, acc1[r2*2+0]);
            acc1[r2*2+1] = fmaf(av.y, bv.y, acc1[r2*2+1]);
        }
    }
    float lm0 = 0.0f, lm1 = 0.0f;
    #pragma unroll
    for (int r = 0; r < 10; ++r) { lm0 = fmaxf(lm0, acc0[r]); lm1 = fmaxf(lm1, acc1[r]); }
    *reinterpret_cast<float2*>(&pm[rg][col0]) = make_float2(lm0, lm1);
    __syncthreads();
    if (tid < 80) {
        float cm = 0.0f;
        #pragma unroll
        for (int r = 0; r < 8; ++r) cm = fmaxf(cm, pm[r][tid]);
        if (cm > 0.0f) { inv[tid] = 1.0f / cm; zc[tid] = zB[tid] + maxA + __logf(cm); }
        else           { inv[tid] = 0.0f;      zc[tid] = -3.0e38f; }
    }
    __syncthreads();
    float s0 = inv[col0], s1 = inv[col0 + 1];
    #pragma unroll
    for (int r = 0; r < 10; ++r) Bg[col0 * 80 + rowb + r] = __float2bfloat16(acc0[r] * s0);
    #pragma unroll
    for (int r = 0; r < 10; ++r) Bg[(col0 + 1) * 80 + rowb + r] = __float2bfloat16(acc1[r] * s1);
    if (tid < 80) zBg[tid] = zc[tid];
}

// ---------------- Kernel E: final partition ----------------
__global__ __launch_bounds__(128) void final_kernel(
    const __hip_bfloat16* __restrict__ Mst, const float* __restrict__ Zst,
    const float* __restrict__ Rst, const float* __restrict__ startv,
    float* __restrict__ partition)
{
    int b = blockIdx.x;
    int tid = threadIdx.x;
    int lane = tid & 63, wv = tid >> 6;
    const __hip_bfloat16* P = Mst + (size_t)b * NC_ * 6400;   // slot 0 product
    const float* zP = Zst + (size_t)b * NC_ * 80;
    const float* R  = Rst + ((size_t)b * NC_ + NC_ - 1) * 400;
    const float* zR = Zst + ((size_t)b * NC_ + NC_ - 1) * 80;
    __shared__ float red[2];
    __shared__ float m1s;

    if (tid == 0) {
        float m1 = -3.0e38f;
        #pragma unroll
        for (int c2 = 0; c2 < C_; ++c2) m1 = fmaxf(m1, zP[c2] + startv[c2]);
        m1s = m1;
    }
    __syncthreads();
    float m1 = m1s;

    float w = 0.0f, zi = -3.0e38f, rsum = 0.0f, zrv = 0.0f;
    if (tid < 80) {
        #pragma unroll
        for (int c2 = 0; c2 < C_; ++c2)
            w = fmaf(__bfloat162float(P[c2 * 80 + tid]), __expf(zP[c2] + startv[c2] - m1), w);
        zrv = zR[tid];
        if (w > 0.0f) zi = zrv;
        rsum = (R[tid*5+0] + R[tid*5+1]) + (R[tid*5+2] + R[tid*5+3]) + R[tid*5+4];
    }
    float m = zi;
    #pragma unroll
    for (int off = 32; off; off >>= 1) m = fmaxf(m, __shfl_xor(m, off, 64));
    if (lane == 0) red[wv] = m;
    __syncthreads();
    float m2 = fmaxf(red[0], red[1]);

    float sv = (tid < 80 && w > 0.0f) ? w * __expf(zrv - m2) * rsum : 0.0f;
    #pragma unroll
    for (int off = 32; off; off >>= 1) sv += __shfl_xor(sv, off, 64);
    if (lane == 0) red[wv] = sv;
    __syncthreads();
    if (tid == 0) partition[b] = m1 + m2 + __logf(red[0] + red[1]);
}

extern "C" void kernel_launch(void* const* d_in, const int* in_sizes, int n_in,
                              void* d_out, int out_size, void* d_ws, size_t ws_size,
                              hipStream_t stream) {
    (void)in_sizes; (void)n_in; (void)out_size; (void)ws_size;
    const float* seq    = (const float*)d_in[0];
    const int*   lens   = (const int*)  d_in[1];
    const float* W_enc  = (const float*)d_in[2];
    const float* b_enc  = (const float*)d_in[3];
    const float* W_proj = (const float*)d_in[4];
    const float* b_proj = (const float*)d_in[5];
    const float* trans  = (const float*)d_in[6];
    const float* startv = (const float*)d_in[7];
    const float* dur    = (const float*)d_in[8];

    float* out       = (float*)d_out;
    float* partition = out;
    float* cum       = out + B_;

    float* emitA = (float*)d_ws;                              // B*C*T f32
    float* emitB = emitA + (size_t)B_ * C_ * T_;              // B*C*T f32
    __hip_bfloat16* Mst = (__hip_bfloat16*)(emitB + (size_t)B_ * C_ * T_);  // B*NC*6400 bf16
    float* Rst = (float*)(Mst + (size_t)B_ * NC_ * 6400);     // B*NC*400 f32
    float* Zst = Rst + (size_t)B_ * NC_ * 400;                // B*NC*80 f32
    float* PA  = Zst + (size_t)B_ * NC_ * 80;                 // 2*B*NTILE*C f32

    encoder_kernel<<<512, 256, 0, stream>>>(seq, W_enc, b_enc, W_proj, b_proj, emitA, emitB, PA);
    chunk_kernel<<<B_ * NC_, 448, 0, stream>>>(emitA, emitB, lens, trans, dur, Mst, Rst, Zst);
    cumwrite_kernel<<<B_ * C_ * NTILE, 64, 0, stream>>>(emitA, emitB, PA, cum);
    tree_kernel<<<B_ * 31, 320, 0, stream>>>(Mst, Zst, 0, 31);
    tree_kernel<<<B_ * 16, 320, 0, stream>>>(Mst, Zst, 1, 16);
    tree_kernel<<<B_ * 8,  320, 0, stream>>>(Mst, Zst, 2, 8);
    tree_kernel<<<B_ * 4,  320, 0, stream>>>(Mst, Zst, 3, 4);
    tree_kernel<<<B_ * 2,  320, 0, stream>>>(Mst, Zst, 4, 2);
    tree_kernel<<<B_ * 1,  320, 0, stream>>>(Mst, Zst, 5, 1);
    final_kernel<<<B_, 128, 0, stream>>>(Mst, Zst, Rst, startv, partition);
}

// Round 6
// 120.093 us; speedup vs baseline: 9.0429x; 1.1695x over previous
//
#include <hip/hip_runtime.h>
#include <hip/hip_bf16.h>

#define B_ 8
#define T_ 8192
#define HID_ 256
#define C_ 5
#define K_ 16
#define NC_ 64    // chunks per batch
#define NTILE 32  // 256-position tiles per batch (cumsum pipeline)
#define GSPAN 144 // 16 pre-window + up to 128 in-window g values
#define NFW 31    // forward-chain matrices (k=0..30); backward takes k=62..31

__device__ __forceinline__ float gelu_tanh(float x) {
    float u = 0.7978845608028654f * (x + 0.044715f * x * x * x);
    float e = __expf(2.0f * u);
    float th = 1.0f - 2.0f / (e + 1.0f);
    return 0.5f * x * (1.0f + th);
}

// ---------------- Kernel A: encoder (hidden split) -> emitA/emitB + per-tile class sums ----------------
__global__ __launch_bounds__(256) void encoder_kernel(
    const float* __restrict__ seq, const float* __restrict__ W_enc,
    const float* __restrict__ b_enc, const float* __restrict__ W_proj,
    const float* __restrict__ b_proj, float* __restrict__ emitA,
    float* __restrict__ emitB, float* __restrict__ PA)
{
    __shared__ float4 we[128];
    __shared__ float  be[128];
    __shared__ float  wp[128 * C_];
    __shared__ float  prd[4][C_];
    int tid = threadIdx.x;
    int half = blockIdx.x >> 8;
    int blk  = blockIdx.x & 255;
    int h0 = half * 128;
    if (tid < 128) {
        int h = h0 + tid;
        we[tid] = make_float4(W_enc[0*HID_+h], W_enc[1*HID_+h], W_enc[2*HID_+h], W_enc[3*HID_+h]);
        be[tid] = b_enc[h];
    }
    for (int i = tid; i < 128 * C_; i += 256) wp[i] = W_proj[h0 * C_ + i];
    __syncthreads();
    int b = blk >> 5;              // 32 tiles per batch
    int tile = blk & 31;
    int t = tile * 256 + tid;
    float4 s = reinterpret_cast<const float4*>(seq)[(size_t)b * T_ + t];
    float a0, a1, a2, a3, a4;
    if (half == 0) { a0 = b_proj[0]; a1 = b_proj[1]; a2 = b_proj[2]; a3 = b_proj[3]; a4 = b_proj[4]; }
    else           { a0 = a1 = a2 = a3 = a4 = 0.0f; }
    #pragma unroll 8
    for (int h = 0; h < 128; ++h) {
        float4 w = we[h];
        float pre = be[h] + s.x*w.x + s.y*w.y + s.z*w.z + s.w*w.w;
        float hd = gelu_tanh(pre);
        a0 = fmaf(hd, wp[h*C_+0], a0);
        a1 = fmaf(hd, wp[h*C_+1], a1);
        a2 = fmaf(hd, wp[h*C_+2], a2);
        a3 = fmaf(hd, wp[h*C_+3], a3);
        a4 = fmaf(hd, wp[h*C_+4], a4);
    }
    float* em = half ? emitB : emitA;
    size_t base = (size_t)b * C_ * T_ + t;
    em[base + 0*T_] = a0;
    em[base + 1*T_] = a1;
    em[base + 2*T_] = a2;
    em[base + 3*T_] = a3;
    em[base + 4*T_] = a4;
    float s0 = a0, s1 = a1, s2 = a2, s3 = a3, s4 = a4;
    #pragma unroll
    for (int off = 1; off < 64; off <<= 1) {
        s0 += __shfl_xor(s0, off, 64);
        s1 += __shfl_xor(s1, off, 64);
        s2 += __shfl_xor(s2, off, 64);
        s3 += __shfl_xor(s3, off, 64);
        s4 += __shfl_xor(s4, off, 64);
    }
    int lane = tid & 63, wv = tid >> 6;
    if (lane == 0) { prd[wv][0]=s0; prd[wv][1]=s1; prd[wv][2]=s2; prd[wv][3]=s3; prd[wv][4]=s4; }
    __syncthreads();
    if (tid < C_) {
        float t4 = (prd[0][tid] + prd[1][tid]) + (prd[2][tid] + prd[3][tid]);
        PA[((half * B_ + b) * NTILE + tile) * C_ + tid] = t4;
    }
}

// ---------------- Kernel B: cum writer (one block per (b,c,tile)) ----------------
__global__ __launch_bounds__(64) void cumwrite_kernel(
    const float* __restrict__ emitA, const float* __restrict__ emitB,
    const float* __restrict__ PA, float* __restrict__ cum)
{
    int bx = blockIdx.x;
    int tile = bx & (NTILE - 1);
    int bc = bx >> 5;               // 0..39
    int b = bc / C_, c = bc - b * C_;
    int lane = threadIdx.x;
    // parallel prefix offset: sum of tile sums tt < tile
    float v = 0.0f;
    if (lane < NTILE && lane < tile)
        v = PA[((0 * B_ + b) * NTILE + lane) * C_ + c]
          + PA[((1 * B_ + b) * NTILE + lane) * C_ + c];
    #pragma unroll
    for (int o = 32; o; o >>= 1) v += __shfl_xor(v, o, 64);
    const float* eA = emitA + ((size_t)b * C_ + c) * T_;
    const float* eB = emitB + ((size_t)b * C_ + c) * T_;
    float* cb = cum + (size_t)b * (T_ + 1) * C_;
    if (tile == 0 && lane == 0) cb[c] = 0.0f;
    float carry = v;
    #pragma unroll
    for (int i = 0; i < 4; ++i) {
        int idx = tile * 256 + i * 64 + lane;
        float e = eA[idx] + eB[idx];
        float si = e;
        #pragma unroll
        for (int o = 1; o < 64; o <<= 1) {
            float n = __shfl_up(si, o, 64);
            if (lane >= o) si += n;
        }
        cb[(size_t)(idx + 1) * C_ + c] = carry + si;
        carry += __shfl(si, 63, 64);
    }
}

// ---------------- Kernel C: per-chunk 80x80 transfer matrices ----------------
#define CHUNK_STEP(PP, GV)                                                    \
    {                                                                         \
        P *= (GV);                                                            \
        float invP = __builtin_amdgcn_rcpf(P);                                \
        float d0 = 0.f, d1 = 0.f, d2 = 0.f, d3 = 0.f;                         \
        d0 = fmaf(W[0],  ed[(0  + (PP)) & 15], d0);                           \
        d1 = fmaf(W[1],  ed[(1  + (PP)) & 15], d1);                           \
        d2 = fmaf(W[2],  ed[(2  + (PP)) & 15], d2);                           \
        d3 = fmaf(W[3],  ed[(3  + (PP)) & 15], d3);                           \
        d0 = fmaf(W[4],  ed[(4  + (PP)) & 15], d0);                           \
        d1 = fmaf(W[5],  ed[(5  + (PP)) & 15], d1);                           \
        d2 = fmaf(W[6],  ed[(6  + (PP)) & 15], d2);                           \
        d3 = fmaf(W[7],  ed[(7  + (PP)) & 15], d3);                           \
        d0 = fmaf(W[8],  ed[(8  + (PP)) & 15], d0);                           \
        d1 = fmaf(W[9],  ed[(9  + (PP)) & 15], d1);                           \
        d2 = fmaf(W[10], ed[(10 + (PP)) & 15], d2);                           \
        d3 = fmaf(W[11], ed[(11 + (PP)) & 15], d3);                           \
        d0 = fmaf(W[12], ed[(12 + (PP)) & 15], d0);                           \
        d1 = fmaf(W[13], ed[(13 + (PP)) & 15], d1);                           \
        d2 = fmaf(W[14], ed[(14 + (PP)) & 15], d2);                           \
        d3 = fmaf(W[15], ed[(15 + (PP)) & 15], d3);                           \
        float dotv = (d0 + d1) + (d2 + d3);                                   \
        astep = P * dotv;                                                     \
        float A0 = __shfl(astep, base5 + 0, 64);                              \
        float A1 = __shfl(astep, base5 + 1, 64);                              \
        float A2 = __shfl(astep, base5 + 2, 64);                              \
        float A3 = __shfl(astep, base5 + 3, 64);                              \
        float A4 = __shfl(astep, base5 + 4, 64);                              \
        A0v = A0;                                                             \
        float Sn = fmaf(eT[0], A0, fmaf(eT[1], A1, fmaf(eT[2], A2,           \
                   fmaf(eT[3], A3, eT[4] * A4))));                            \
        W[15 - (PP)] = Sn * invP;                                             \
    }

#define CHUNK_RENORM()                                                        \
    {                                                                         \
        bool ok = (A0v > 1e-30f);                                             \
        float r  = ok ? __builtin_amdgcn_rcpf(A0v) : 1.0f;                    \
        float lz = ok ? __logf(A0v) : 0.0f;                                   \
        float f = P * r;                                                      \
        _Pragma("unroll") for (int q = 0; q < 16; ++q) W[q] *= f;             \
        P = 1.0f; z += lz;                                                    \
    }

#define TAIL_STEP(PP, GV)                                                     \
    if ((PP) < rem) {                                                         \
        CHUNK_STEP(PP, GV);                                                   \
        if ((PP) == rem - 1) Afin = astep;                                    \
    }

__global__ __launch_bounds__(448) void chunk_kernel(
    const float* __restrict__ emitA, const float* __restrict__ emitB,
    const int* __restrict__ lengths, const float* __restrict__ trans,
    const float* __restrict__ dur, __hip_bfloat16* __restrict__ Mout,
    float* __restrict__ Rout, float* __restrict__ Zout,
    float* __restrict__ Zmx)
{
    __shared__ float g_lds[C_][GSPAN + 4];
    __shared__ float zl[80];
    __shared__ float zredv;
    int blk = blockIdx.x;
    int b = blk >> 6, k = blk & (NC_ - 1);
    int len = lengths[b];
    int s = (k * len) >> 6;
    int e = ((k + 1) * len) >> 6;
    int L = e - s;                       // 64..128
    int tid = threadIdx.x;

    for (int i = tid; i < C_ * GSPAN; i += 448) {
        int cc = i / GSPAN, j = i - cc * GSPAN;
        int pos = s - 16 + j;
        float val = 1.0f;
        if (pos >= 0 && j < 16 + L) {
            size_t gidx = ((size_t)b * C_ + cc) * T_ + pos;
            val = __expf(emitA[gidx] + emitB[gidx]);
        }
        g_lds[cc][j] = val;
    }
    __syncthreads();

    int lane = tid & 63, wv = tid >> 6;
    int cin = lane / 5;                  // 0..12
    int c = lane - cin * 5;
    int col = wv * 12 + cin;
    bool active = (cin < 12) && (col < 80);
    int base5 = (cin < 12) ? (cin * 5) : 0;

    float ed[K_], eT[C_];
    #pragma unroll
    for (int j = 0; j < K_; ++j) ed[j] = __expf(dur[c * K_ + j]);
    #pragma unroll
    for (int cc = 0; cc < C_; ++cc) eT[cc] = __expf(trans[cc * C_ + c]);

    float W[K_];
    #pragma unroll
    for (int j = 0; j < K_; ++j) W[j] = 0.0f;
    if (active) {
        int j0 = col / 5;
        int c0 = col - j0 * 5;
        if (c == c0) {
            float v = 1.0f;
            for (int j = 16 - j0; j < 16; ++j) v *= g_lds[c][j];
            #pragma unroll
            for (int j = 0; j < K_; ++j) if (j == j0) W[j] = v;
        }
    }

    float P = 1.0f, z = 0.0f, Afin = 0.0f, astep = 0.0f, A0v = 0.0f;
    int nfull = (L - 1) >> 4;
    int rem = L - (nfull << 4);
    int tl0 = 0;

    for (int bi = 0; bi < nfull; ++bi) {
        const float4* gp = reinterpret_cast<const float4*>(&g_lds[c][16 + tl0]);
        float4 ga = gp[0], gb = gp[1], gc = gp[2], gd = gp[3];
        CHUNK_STEP(0,  ga.x); CHUNK_STEP(1,  ga.y); CHUNK_STEP(2,  ga.z); CHUNK_STEP(3,  ga.w);
        CHUNK_STEP(4,  gb.x); CHUNK_STEP(5,  gb.y); CHUNK_STEP(6,  gb.z); CHUNK_STEP(7,  gb.w);
        CHUNK_STEP(8,  gc.x); CHUNK_STEP(9,  gc.y); CHUNK_STEP(10, gc.z); CHUNK_STEP(11, gc.w);
        CHUNK_STEP(12, gd.x); CHUNK_STEP(13, gd.y); CHUNK_STEP(14, gd.z); CHUNK_STEP(15, gd.w);
        CHUNK_RENORM();
        tl0 += 16;
    }
    {
        const float4* gp = reinterpret_cast<const float4*>(&g_lds[c][16 + tl0]);
        float4 ga = gp[0], gb = gp[1], gc = gp[2], gd = gp[3];
        TAIL_STEP(0,  ga.x); TAIL_STEP(1,  ga.y); TAIL_STEP(2,  ga.z); TAIL_STEP(3,  ga.w);
        TAIL_STEP(4,  gb.x); TAIL_STEP(5,  gb.y); TAIL_STEP(6,  gb.z); TAIL_STEP(7,  gb.w);
        TAIL_STEP(8,  gc.x); TAIL_STEP(9,  gc.y); TAIL_STEP(10, gc.z); TAIL_STEP(11, gc.w);
        TAIL_STEP(12, gd.x); TAIL_STEP(13, gd.y); TAIL_STEP(14, gd.z); TAIL_STEP(15, gd.w);
    }

    // epilogue: per-block zmax reduction, then stores (ez = exp(z - zmax))
    if (active && c == 0) zl[col] = z;
    __syncthreads();
    if (tid < 64) {
        float m = zl[tid];
        if (tid < 16) m = fmaxf(m, zl[tid + 64]);
        #pragma unroll
        for (int off = 32; off; off >>= 1) m = fmaxf(m, __shfl_xor(m, off, 64));
        if (tid == 0) zredv = m;
    }
    __syncthreads();
    float zm = zredv;
    if (tid == 0) Zmx[blk] = zm;

    if (active) {
        int pn = L & 15;
        size_t ob = ((size_t)blk * 80 + col) * 80;
        if (k < NC_ - 1) {               // last chunk's M never used
            #pragma unroll
            for (int slot = 0; slot < 16; ++slot) {
                int j = (slot + pn) & 15;
                float pr = 1.0f;
                for (int i2 = L - j; i2 < L; ++i2) pr *= g_lds[c][16 + i2];
                Mout[ob + j * C_ + c] =
                    __float2bfloat16(W[slot] * P * __builtin_amdgcn_rcpf(pr));
            }
        }
        Rout[(size_t)blk * 400 + col * C_ + c] = Afin;
        if (c == 0) Zout[(size_t)blk * 80 + col] = __expf(z - zm);
    }
}

// ---------------- Kernel D: forward/backward vector chains ----------------
// grid 16: block (b, dir). dir0: x = M_30···M_0·x0. dir1: u^T = (rs∘ez)^T·M_62···M_31.
__global__ __launch_bounds__(320) void chain_kernel(
    const __hip_bfloat16* __restrict__ Mst, const float* __restrict__ ezZ,
    const float* __restrict__ Zmx, const float* __restrict__ Rst,
    const float* __restrict__ startv, float* __restrict__ Uvec,
    float* __restrict__ Xvec, float* __restrict__ Zu, float* __restrict__ Zx)
{
    __shared__ float vin[80];
    __shared__ float sv[80];
    __shared__ float part[4][80];
    __shared__ float red;
    int b = blockIdx.x >> 1;
    int dir = blockIdx.x & 1;
    int tid = threadIdx.x;
    float Z = 0.0f;

    if (dir == 0) {
        if (tid < 80) vin[tid] = (tid < C_) ? __expf(startv[tid]) : 0.0f;
        __syncthreads();
        int r = tid % 80, grp = tid / 80, q0 = grp * 20;
        for (int k = 0; k < NFW; ++k) {
            const __hip_bfloat16* base = Mst + (size_t)(b * NC_ + k) * 6400;
            const float* ez = ezZ + (size_t)(b * NC_ + k) * 80;
            __hip_bfloat16 nv[20];
            #pragma unroll
            for (int i = 0; i < 20; ++i) nv[i] = base[(q0 + i) * 80 + r];
            if (tid < 80) sv[tid] = vin[tid] * ez[tid];
            __syncthreads();
            float p = 0.0f;
            #pragma unroll
            for (int i = 0; i < 20; ++i)
                p = fmaf(__bfloat162float(nv[i]), sv[q0 + i], p);
            part[grp][r] = p;
            __syncthreads();
            if (tid < 80)
                sv[tid] = (part[0][tid] + part[1][tid]) + (part[2][tid] + part[3][tid]);
            __syncthreads();
            if (tid < 64) {
                float m = sv[tid];
                if (tid < 16) m = fmaxf(m, sv[tid + 64]);
                #pragma unroll
                for (int off = 32; off; off >>= 1) m = fmaxf(m, __shfl_xor(m, off, 64));
                if (tid == 0) red = m;
            }
            __syncthreads();
            float rm = red;
            if (tid < 80) vin[tid] = sv[tid] / rm;
            Z += Zmx[b * NC_ + k] + __logf(rm);
            __syncthreads();
        }
        if (tid < 80) Xvec[b * 80 + tid] = vin[tid];
        if (tid == 0) Zx[b] = Z;
    } else {
        int last = b * NC_ + NC_ - 1;
        if (tid < 80) {
            const float* R = Rst + (size_t)last * 400 + tid * 5;
            float rs = ((R[0] + R[1]) + (R[2] + R[3])) + R[4];
            sv[tid] = rs * ezZ[(size_t)last * 80 + tid];
        }
        __syncthreads();
        if (tid < 64) {
            float m = sv[tid];
            if (tid < 16) m = fmaxf(m, sv[tid + 64]);
            #pragma unroll
            for (int off = 32; off; off >>= 1) m = fmaxf(m, __shfl_xor(m, off, 64));
            if (tid == 0) red = m;
        }
        __syncthreads();
        {
            float rm = red;
            if (tid < 80) vin[tid] = sv[tid] / rm;
            Z = Zmx[last] + __logf(rm);
        }
        __syncthreads();
        int q = tid % 80, rg = tid / 80;
        for (int k = NC_ - 2; k >= NFW; --k) {
            const __hip_bfloat16* base = Mst + (size_t)(b * NC_ + k) * 6400;
            const float* ez = ezZ + (size_t)(b * NC_ + k) * 80;
            ushort2 nv[10];
            const ushort2* mp = reinterpret_cast<const ushort2*>(base + q * 80 + rg * 20);
            #pragma unroll
            for (int i = 0; i < 10; ++i) nv[i] = mp[i];
            float p = 0.0f;
            #pragma unroll
            for (int i = 0; i < 10; ++i) {
                __hip_bfloat16 h0 = *reinterpret_cast<const __hip_bfloat16*>(&nv[i].x);
                __hip_bfloat16 h1 = *reinterpret_cast<const __hip_bfloat16*>(&nv[i].y);
                p = fmaf(__bfloat162float(h0), vin[rg * 20 + 2 * i + 0], p);
                p = fmaf(__bfloat162float(h1), vin[rg * 20 + 2 * i + 1], p);
            }
            part[rg][q] = p;
            __syncthreads();
            if (tid < 80)
                sv[tid] = ((part[0][tid] + part[1][tid]) + (part[2][tid] + part[3][tid])) * ez[tid];
            __syncthreads();
            if (tid < 64) {
                float m = sv[tid];
                if (tid < 16) m = fmaxf(m, sv[tid + 64]);
                #pragma unroll
                for (int off = 32; off; off >>= 1) m = fmaxf(m, __shfl_xor(m, off, 64));
                if (tid == 0) red = m;
            }
            __syncthreads();
            float rm = red;
            if (tid < 80) vin[tid] = sv[tid] / rm;
            Z += Zmx[b * NC_ + k] + __logf(rm);
            __syncthreads();
        }
        if (tid < 80) Uvec[b * 80 + tid] = vin[tid];
        if (tid == 0) Zu[b] = Z;
    }
}

// ---------------- Kernel E: meet -> partition ----------------
__global__ __launch_bounds__(512) void meet_kernel(
    const float* __restrict__ Uvec, const float* __restrict__ Xvec,
    const float* __restrict__ Zu, const float* __restrict__ Zx,
    float* __restrict__ partition)
{
    int tid = threadIdx.x;
    int b = tid >> 6, lane = tid & 63;
    float v = Uvec[b * 80 + lane] * Xvec[b * 80 + lane];
    if (lane < 16) v += Uvec[b * 80 + 64 + lane] * Xvec[b * 80 + 64 + lane];
    #pragma unroll
    for (int off = 32; off; off >>= 1) v += __shfl_xor(v, off, 64);
    if (lane == 0) partition[b] = Zu[b] + Zx[b] + __logf(v);
}

extern "C" void kernel_launch(void* const* d_in, const int* in_sizes, int n_in,
                              void* d_out, int out_size, void* d_ws, size_t ws_size,
                              hipStream_t stream) {
    (void)in_sizes; (void)n_in; (void)out_size; (void)ws_size;
    const float* seq    = (const float*)d_in[0];
    const int*   lens   = (const int*)  d_in[1];
    const float* W_enc  = (const float*)d_in[2];
    const float* b_enc  = (const float*)d_in[3];
    const float* W_proj = (const float*)d_in[4];
    const float* b_proj = (const float*)d_in[5];
    const float* trans  = (const float*)d_in[6];
    const float* startv = (const float*)d_in[7];
    const float* dur    = (const float*)d_in[8];

    float* out       = (float*)d_out;
    float* partition = out;
    float* cum       = out + B_;

    float* emitA = (float*)d_ws;                              // B*C*T f32
    float* emitB = emitA + (size_t)B_ * C_ * T_;              // B*C*T f32
    __hip_bfloat16* Mst = (__hip_bfloat16*)(emitB + (size_t)B_ * C_ * T_);  // B*NC*6400 bf16
    float* Rst = (float*)(Mst + (size_t)B_ * NC_ * 6400);     // B*NC*400 f32
    float* Zst = Rst + (size_t)B_ * NC_ * 400;                // B*NC*80 f32 (ez)
    float* Zmx = Zst + (size_t)B_ * NC_ * 80;                 // B*NC f32
    float* PA  = Zmx + (size_t)B_ * NC_;                      // 2*B*NTILE*C f32
    float* Uv  = PA  + 2 * B_ * NTILE * C_;                   // B*80
    float* Xv  = Uv  + B_ * 80;                               // B*80
    float* Zu  = Xv  + B_ * 80;                               // B
    float* Zx  = Zu  + B_;                                    // B

    encoder_kernel<<<512, 256, 0, stream>>>(seq, W_enc, b_enc, W_proj, b_proj, emitA, emitB, PA);
    chunk_kernel<<<B_ * NC_, 448, 0, stream>>>(emitA, emitB, lens, trans, dur, Mst, Rst, Zst, Zmx);
    cumwrite_kernel<<<B_ * C_ * NTILE, 64, 0, stream>>>(emitA, emitB, PA, cum);
    chain_kernel<<<16, 320, 0, stream>>>(Mst, Zst, Zmx, Rst, startv, Uv, Xv, Zu, Zx);
    meet_kernel<<<1, 512, 0, stream>>>(Uv, Xv, Zu, Zx, partition);
}